// Round 4
// baseline (926.212 us; speedup 1.0000x reference)
//
#include <hip/hip_runtime.h>
#include <hip/hip_bf16.h>
#include <cstdint>

// GGNN encoder, B=4, N=1024, DIN=D=256, E=5, STEP=5.
// Round 4: dtype-robust. A sniffer detects whether inputs are fp32 (per the
// reference file) or bf16 (per the test label); weights are ingested to
// internal bf16 once; big external tensors (node_features, adj) are staged
// through a flag-aware loader; outputs stored in the detected dtype.
// Core pipeline = Round 3: acc = sum_e adj_e @ (h @ W_e^T), bf16 MFMA 16x16x32.

typedef __attribute__((ext_vector_type(8))) short bf16x8;
typedef __attribute__((ext_vector_type(4))) float f32x4;

__device__ __forceinline__ float bf2f(__hip_bfloat16 x) { return __bfloat162float(x); }
__device__ __forceinline__ __hip_bfloat16 f2bf(float x) { return __float2bfloat16(x); }
__device__ __forceinline__ short f2bs(float x) {
  __hip_bfloat16 h = __float2bfloat16(x);
  return *reinterpret_cast<short*>(&h);
}

// load 8 consecutive elements of an external tensor as bf16x8
__device__ __forceinline__ bf16x8 ld8_ext(const void* base, long off, bool f32) {
  if (f32) {
    const float* p = (const float*)base + off;
    bf16x8 r;
#pragma unroll
    for (int i = 0; i < 8; ++i) r[i] = f2bs(p[i]);
    return r;
  }
  return *(const bf16x8*)((const __hip_bfloat16*)base + off);
}

// ---- dtype sniffer: writes flag (1 = fp32 inputs, 0 = bf16 inputs) ----
// Looks at the HIGH byte of the LOW 16 bits of 512 uint32 words of adj.
// fp32 adj (uniform[0,2e-3]): that byte is mantissa -> ~uniform -> ~10% in band.
// bf16-packed adj: low short IS a small positive bf16 -> byte in [0x28,0x40].
__global__ void detect_dtype(const uint32_t* __restrict__ raw, int* __restrict__ flag) {
  __shared__ int cnt;
  if (threadIdx.x == 0) cnt = 0;
  __syncthreads();
  int c = 0;
  for (int i = threadIdx.x; i < 512; i += 256) {
    uint32_t byte = (raw[i] >> 8) & 0xFF;
    if (byte >= 0x28 && byte <= 0x40) ++c;
  }
  atomicAdd(&cnt, c);
  __syncthreads();
  if (threadIdx.x == 0) *flag = (cnt < 300) ? 1 : 0;
}

// fp32 bias pool: [0:256) fc_b | [256:1024) b_ih | [1024:1792) b_hh |
// [1792:2048) conv1_b | [2048:2304) conv2_b | [2304:2560) sum_e edge_b
__global__ void prep_pool(const void* fcb, const void* bih, const void* bhh,
                          const void* c1b, const void* c2b, const void* edgeb,
                          const int* __restrict__ flag,
                          float* __restrict__ pool, float* __restrict__ ge) {
  const bool f32 = (*flag != 0);
  for (int t = threadIdx.x; t < 2560; t += 256) {
    float v;
    const void* p; int i;
    if (t < 256)       { p = fcb;  i = t; }
    else if (t < 1024) { p = bih;  i = t - 256; }
    else if (t < 1792) { p = bhh;  i = t - 1024; }
    else if (t < 2048) { p = c1b;  i = t - 1792; }
    else if (t < 2304) { p = c2b;  i = t - 2048; }
    else {
      int k = t - 2304; float s = 0.f;
      for (int e = 0; e < 5; ++e)
        s += f32 ? ((const float*)edgeb)[e * 256 + k]
                 : bf2f(((const __hip_bfloat16*)edgeb)[e * 256 + k]);
      pool[t] = s; continue;
    }
    v = f32 ? ((const float*)p)[i] : bf2f(((const __hip_bfloat16*)p)[i]);
    pool[t] = v;
  }
  for (int t = threadIdx.x; t < 1024; t += 256) ge[t] = 0.f;
}

// ingest all 6 weight matrices into one internal bf16 pool
// layout: fc_w@0(65536) edge_w@65536(327680) w_ih@393216(196608)
//         w_hh@589824(196608) c1w@786432(65536) c2w@851968(65536)
__global__ void wcvt_all(const void* fcw, const void* edw, const void* wih,
                         const void* whh, const void* c1w, const void* c2w,
                         const int* __restrict__ flag, __hip_bfloat16* __restrict__ dst) {
  const bool f32 = (*flag != 0);
  const int i = blockIdx.x * 256 + threadIdx.x;   // 0..917503
  const void* src; int off;
  if      (i < 65536)  { src = fcw; off = i; }
  else if (i < 393216) { src = edw; off = i - 65536; }
  else if (i < 589824) { src = wih; off = i - 393216; }
  else if (i < 786432) { src = whh; off = i - 589824; }
  else if (i < 851968) { src = c1w; off = i - 786432; }
  else                 { src = c2w; off = i - 851968; }
  dst[i] = f32 ? f2bf(((const float*)src)[off])
               : ((const __hip_bfloat16*)src)[off];
}

// OUT_MODE: 0 = bf16 C row-major; 1 = fp32 C row-major; 3 = bf16 C transposed
// A_EXT: A is an external tensor (dtype per *flag); B is always internal bf16.
template<int OUT_MODE, bool HAS_BIAS, bool A_EXT>
__global__ __launch_bounds__(256)
void gemm_bt(const void* __restrict__ A,
             const __hip_bfloat16* __restrict__ Bt,
             const float* __restrict__ bias,
             void* __restrict__ Cp, const int* __restrict__ flag,
             int Kg, int ngrp, int lda, int ldb, int ldc,
             long aBatch, int zdivA, long bBatch, int zdivB, int zmodB,
             long cBatch, long aGrp, long bGrp)
{
  __shared__ __align__(16) __hip_bfloat16 sA[64 * 64];
  __shared__ __align__(16) __hip_bfloat16 sB[64 * 64];
  const bool af32 = A_EXT ? (*flag != 0) : false;
  const int t = threadIdx.x;
  const int w = t >> 6;
  const int l = t & 63;
  const int m0 = blockIdx.x * 64;
  const int n0 = blockIdx.y * 64;
  const int z  = blockIdx.z;

  const long aOff = (long)(z / zdivA) * aBatch;
  const __hip_bfloat16* Bb = Bt + (long)((z / zdivB) % zmodB) * bBatch;

  // staging: 16B chunk p -> LDS(row=p>>3, slot=p&7); slot s of row r holds
  // data chunk s ^ (r&7)  (XOR swizzle -> fragment ds_read_b128 conflict-free)
  const int p0 = t, p1 = t + 256;
  const int sr0 = p0 >> 3, sc0 = (p0 & 7) ^ (sr0 & 7);
  const int sr1 = p1 >> 3, sc1 = (p1 & 7) ^ (sr1 & 7);

  f32x4 acc[4];
#pragma unroll
  for (int i = 0; i < 4; ++i) acc[i] = (f32x4){0.f, 0.f, 0.f, 0.f};

  const int mrow = w * 16 + (l & 15);
  const int quad = l >> 4;

  for (int g = 0; g < ngrp; ++g) {
    const long aG = aOff + (long)g * aGrp;
    const __hip_bfloat16* Bg = Bb + (long)g * bGrp;
    for (int k0 = 0; k0 < Kg; k0 += 64) {
      bf16x8 a0 = ld8_ext(A, aG + (long)(m0 + sr0) * lda + (k0 + sc0 * 8), af32);
      bf16x8 a1 = ld8_ext(A, aG + (long)(m0 + sr1) * lda + (k0 + sc1 * 8), af32);
      bf16x8 b0 = *(const bf16x8*)(Bg + (long)(n0 + sr0) * ldb + (k0 + sc0 * 8));
      bf16x8 b1 = *(const bf16x8*)(Bg + (long)(n0 + sr1) * ldb + (k0 + sc1 * 8));
      __syncthreads();
      *(bf16x8*)(sA + p0 * 8) = a0;
      *(bf16x8*)(sA + p1 * 8) = a1;
      *(bf16x8*)(sB + p0 * 8) = b0;
      *(bf16x8*)(sB + p1 * 8) = b1;
      __syncthreads();
#pragma unroll
      for (int ks = 0; ks < 2; ++ks) {
        const int cg = ks * 4 + quad;
        bf16x8 af = *(const bf16x8*)(sA + mrow * 64 + ((cg ^ (mrow & 7)) * 8));
#pragma unroll
        for (int t4 = 0; t4 < 4; ++t4) {
          const int nrow = t4 * 16 + (l & 15);
          bf16x8 bfr = *(const bf16x8*)(sB + nrow * 64 + ((cg ^ (nrow & 7)) * 8));
          acc[t4] = __builtin_amdgcn_mfma_f32_16x16x32_bf16(af, bfr, acc[t4], 0, 0, 0);
        }
      }
    }
  }

  // C/D layout: col = lane&15, row = (lane>>4)*4 + reg
#pragma unroll
  for (int t4 = 0; t4 < 4; ++t4) {
    const int n = n0 + t4 * 16 + (l & 15);
    float bv = 0.f;
    if (HAS_BIAS) bv = bias[n];
    if (OUT_MODE == 3) {
      __hip_bfloat16 tmp[4];
#pragma unroll
      for (int r = 0; r < 4; ++r) tmp[r] = f2bf(acc[t4][r] + bv);
      __hip_bfloat16* cb = (__hip_bfloat16*)Cp + (long)z * cBatch +
                           (long)n * ldc + (m0 + w * 16 + quad * 4);
      *(ushort4*)cb = *(const ushort4*)tmp;
    } else {
#pragma unroll
      for (int r = 0; r < 4; ++r) {
        const int m = m0 + w * 16 + quad * 4 + r;
        const float v = acc[t4][r] + bv;
        if (OUT_MODE == 0)
          ((__hip_bfloat16*)Cp)[(long)z * cBatch + (long)m * ldc + n] = f2bf(v);
        else
          ((float*)Cp)[(long)z * cBatch + (long)m * ldc + n] = v;
      }
    }
  }
}

// torch GRUCell gates [r,z,n]; h kept bf16 internally
__global__ void gru_gate(const __hip_bfloat16* __restrict__ gi,
                         const __hip_bfloat16* __restrict__ gh,
                         __hip_bfloat16* __restrict__ hbf)
{
  const int m = blockIdx.x;
  const int k = threadIdx.x;
  const long gb = (long)m * 768;
  const float ir = bf2f(gi[gb + k]);
  const float iz = bf2f(gi[gb + 256 + k]);
  const float inn = bf2f(gi[gb + 512 + k]);
  const float hr = bf2f(gh[gb + k]);
  const float hz = bf2f(gh[gb + 256 + k]);
  const float hn = bf2f(gh[gb + 512 + k]);
  const long hidx = (long)m * 256 + k;
  const float h = bf2f(hbf[hidx]);
  const float r = 1.f / (1.f + __expf(-(ir + hr)));
  const float zz = 1.f / (1.f + __expf(-(iz + hz)));
  const float nn = tanhf(inn + r * hn);
  hbf[hidx] = f2bf((1.f - zz) * nn + zz * h);
}

__global__ void epilogue(const float* __restrict__ attnl,
                         const float* __restrict__ featl,
                         const __hip_bfloat16* __restrict__ hbf,
                         float* __restrict__ ge,
                         void* __restrict__ dout, const int* __restrict__ flag)
{
  const bool f32 = (*flag != 0);
  const int b = blockIdx.x;
  const int chunk = blockIdx.y;
  const int k = threadIdx.x;
  __shared__ float red[4];
  float gacc = 0.f;
  for (int i = 0; i < 64; ++i) {
    const int node = chunk * 64 + i;
    const long idx = ((long)b * 1024 + node) * 256 + k;
    const float a = 1.f / (1.f + __expf(-attnl[idx]));
    const float f = tanhf(featl[idx]);
    gacc += a * f;
    const float hv = bf2f(hbf[idx]);
    if (f32) ((float*)dout)[1024 + idx] = hv;
    else     ((__hip_bfloat16*)dout)[1024 + idx] = hbf[idx];
    float s = a;
    for (int off = 32; off; off >>= 1) s += __shfl_down(s, off, 64);
    if ((k & 63) == 0) red[k >> 6] = s;
    __syncthreads();
    if (k == 0) {
      const float am = (red[0] + red[1] + red[2] + red[3]) * (1.f / 256.f);
      if (f32) ((float*)dout)[1049600 + b * 1024 + node] = am;
      else     ((__hip_bfloat16*)dout)[1049600 + b * 1024 + node] = f2bf(am);
    }
    __syncthreads();
  }
  atomicAdd(&ge[b * 256 + k], gacc);
}

__global__ void ge_finish(const float* __restrict__ ge, void* __restrict__ dout,
                          const int* __restrict__ flag)
{
  const bool f32 = (*flag != 0);
  const int t = blockIdx.x * 256 + threadIdx.x;   // 0..1023
  if (f32) ((float*)dout)[t] = ge[t];
  else     ((__hip_bfloat16*)dout)[t] = f2bf(ge[t]);
}

extern "C" void kernel_launch(void* const* d_in, const int* in_sizes, int n_in,
                              void* d_out, int out_size, void* d_ws, size_t ws_size,
                              hipStream_t stream) {
  (void)in_sizes; (void)n_in; (void)out_size; (void)ws_size;
  const void* node_f = d_in[0];
  const void* adj    = d_in[1];
  const void* fc_w   = d_in[2];
  const void* fc_b   = d_in[3];
  const void* edge_w = d_in[4];
  const void* edge_b = d_in[5];
  const void* w_ih   = d_in[6];
  const void* w_hh   = d_in[7];
  const void* b_ih   = d_in[8];
  const void* b_hh   = d_in[9];
  const void* c1w    = d_in[10];
  const void* c1b    = d_in[11];
  const void* c2w    = d_in[12];
  const void* c2b    = d_in[13];

  // workspace (~15.8 MiB total):
  //  [0,4)          flag
  //  [256,10496)    fp32 bias pool (2560 f)
  //  [10496,14592)  ge accumulator (1024 f)
  //  [14592,..)     wbf: weights bf16 (917504 elems, 1835008 B)
  //  [1849600,..)   hbf [4096][256] bf16 (2 MiB)
  //  S=[3946752,..) 12 MiB: heT[20][256][1024] (10M) | accb (2M @+10M)
  //                 then gi (6M @0) gh (6M @+6M); then attl f32 (4M @0), fetl (4M @+4M)
  char* ws = (char*)d_ws;
  int*            flag = (int*)(ws);
  float*          bp   = (float*)(ws + 256);
  float*          ge   = (float*)(ws + 10496);
  __hip_bfloat16* wbf  = (__hip_bfloat16*)(ws + 14592);
  __hip_bfloat16* hbf  = (__hip_bfloat16*)(ws + 1849600);
  char*           S    = ws + 3946752;
  __hip_bfloat16* heT  = (__hip_bfloat16*)(S);
  __hip_bfloat16* accb = (__hip_bfloat16*)(S + 10485760);
  __hip_bfloat16* gi   = (__hip_bfloat16*)(S);
  __hip_bfloat16* gh   = (__hip_bfloat16*)(S + 6291456);
  float*          attl = (float*)(S);
  float*          fetl = (float*)(S + 4194304);

  detect_dtype<<<1, 256, 0, stream>>>((const uint32_t*)adj, flag);
  prep_pool<<<1, 256, 0, stream>>>(fc_b, b_ih, b_hh, c1b, c2b, edge_b, flag, bp, ge);
  wcvt_all<<<3584, 256, 0, stream>>>(fc_w, edge_w, w_ih, w_hh, c1w, c2w, flag, wbf);

  // h = X @ fc_w^T + fc_b
  gemm_bt<0, true, true><<<dim3(64, 4, 1), 256, 0, stream>>>(
      node_f, wbf + 0, bp + 0, hbf, flag,
      256, 1, 256, 256, 256, 0, 1, 0, 1, 1, 0, 0, 0);

  for (int s = 0; s < 5; ++s) {
    // heT[b,e] = (h[b] @ edge_w[e]^T)^T  (z=b*5+e, transposed bf16 store)
    gemm_bt<3, false, false><<<dim3(16, 4, 20), 256, 0, stream>>>(
        hbf, wbf + 65536, nullptr, heT, flag,
        256, 1, 256, 256, 1024,
        (long)1024 * 256, 5, 65536, 1, 5,
        (long)256 * 1024, 0, 0);
    // acc[b] = sum_e adj[b,e] @ he[b,e] + sum_edge_b  (grouped K over e)
    gemm_bt<0, true, true><<<dim3(16, 4, 4), 256, 0, stream>>>(
        adj, heT, bp + 2304, accb, flag,
        1024, 5, 1024, 1024, 256,
        (long)5 * 1024 * 1024, 1, (long)5 * 256 * 1024, 1, 4,
        (long)1024 * 256, (long)1024 * 1024, (long)256 * 1024);
    // gi = acc @ w_ih^T + b_ih ; gh = h @ w_hh^T + b_hh
    gemm_bt<0, true, false><<<dim3(64, 12, 1), 256, 0, stream>>>(
        accb, wbf + 393216, bp + 256, gi, flag,
        256, 1, 256, 256, 768, 0, 1, 0, 1, 1, 0, 0, 0);
    gemm_bt<0, true, false><<<dim3(64, 12, 1), 256, 0, stream>>>(
        hbf, wbf + 589824, bp + 1024, gh, flag,
        256, 1, 256, 256, 768, 0, 1, 0, 1, 1, 0, 0, 0);
    gru_gate<<<4096, 256, 0, stream>>>(gi, gh, hbf);
  }

  gemm_bt<1, true, false><<<dim3(64, 4, 1), 256, 0, stream>>>(
      hbf, wbf + 786432, bp + 1792, attl, flag,
      256, 1, 256, 256, 256, 0, 1, 0, 1, 1, 0, 0, 0);
  gemm_bt<1, true, false><<<dim3(64, 4, 1), 256, 0, stream>>>(
      hbf, wbf + 851968, bp + 2048, fetl, flag,
      256, 1, 256, 256, 256, 0, 1, 0, 1, 1, 0, 0, 0);

  epilogue<<<dim3(4, 16), 256, 0, stream>>>(attl, fetl, hbf, ge, d_out, flag);
  ge_finish<<<4, 256, 0, stream>>>(ge, d_out, flag);
}

// Round 5
// 600.846 us; speedup vs baseline: 1.5415x; 1.5415x over previous
//
#include <hip/hip_runtime.h>
#include <hip/hip_bf16.h>
#include <cstdint>

// GGNN encoder, B=4, N=1024, DIN=D=256, E=5, STEP=5. Inputs fp32 (sniffed).
// Round 5: acc GEMM was 5x144us at 11% occupancy (256 blocks = 4 waves/CU,
// latency-bound). Fix: split-K over edge types (1280 blocks, fp32 atomicAdd)
// + one-time adj fp32->bf16 conversion (halves fetch, kills cvt in hot loop).

typedef __attribute__((ext_vector_type(8))) short bf16x8;
typedef __attribute__((ext_vector_type(4))) float f32x4;

__device__ __forceinline__ float bf2f(__hip_bfloat16 x) { return __bfloat162float(x); }
__device__ __forceinline__ __hip_bfloat16 f2bf(float x) { return __float2bfloat16(x); }
__device__ __forceinline__ short f2bs(float x) {
  __hip_bfloat16 h = __float2bfloat16(x);
  return *reinterpret_cast<short*>(&h);
}

// load 8 consecutive elements of an external tensor as bf16x8
__device__ __forceinline__ bf16x8 ld8_ext(const void* base, long off, bool f32) {
  if (f32) {
    const float* p = (const float*)base + off;
    bf16x8 r;
#pragma unroll
    for (int i = 0; i < 8; ++i) r[i] = f2bs(p[i]);
    return r;
  }
  return *(const bf16x8*)((const __hip_bfloat16*)base + off);
}

// ---- dtype sniffer: flag = 1 if inputs are fp32, 0 if bf16 ----
__global__ void detect_dtype(const uint32_t* __restrict__ raw, int* __restrict__ flag) {
  __shared__ int cnt;
  if (threadIdx.x == 0) cnt = 0;
  __syncthreads();
  int c = 0;
  for (int i = threadIdx.x; i < 512; i += 256) {
    uint32_t byte = (raw[i] >> 8) & 0xFF;
    if (byte >= 0x28 && byte <= 0x40) ++c;
  }
  atomicAdd(&cnt, c);
  __syncthreads();
  if (threadIdx.x == 0) *flag = (cnt < 300) ? 1 : 0;
}

// fp32 bias pool: [0:256) fc_b | [256:1024) b_ih | [1024:1792) b_hh |
// [1792:2048) conv1_b | [2048:2304) conv2_b | [2304:2560) sum_e edge_b
__global__ void prep_pool(const void* fcb, const void* bih, const void* bhh,
                          const void* c1b, const void* c2b, const void* edgeb,
                          const int* __restrict__ flag,
                          float* __restrict__ pool, float* __restrict__ ge) {
  const bool f32 = (*flag != 0);
  for (int t = threadIdx.x; t < 2560; t += 256) {
    const void* p; int i;
    if (t < 256)       { p = fcb;  i = t; }
    else if (t < 1024) { p = bih;  i = t - 256; }
    else if (t < 1792) { p = bhh;  i = t - 1024; }
    else if (t < 2048) { p = c1b;  i = t - 1792; }
    else if (t < 2304) { p = c2b;  i = t - 2048; }
    else {
      int k = t - 2304; float s = 0.f;
      for (int e = 0; e < 5; ++e)
        s += f32 ? ((const float*)edgeb)[e * 256 + k]
                 : bf2f(((const __hip_bfloat16*)edgeb)[e * 256 + k]);
      pool[t] = s; continue;
    }
    pool[t] = f32 ? ((const float*)p)[i] : bf2f(((const __hip_bfloat16*)p)[i]);
  }
  for (int t = threadIdx.x; t < 1024; t += 256) ge[t] = 0.f;
}

// ingest all 6 weight matrices into one internal bf16 pool
__global__ void wcvt_all(const void* fcw, const void* edw, const void* wih,
                         const void* whh, const void* c1w, const void* c2w,
                         const int* __restrict__ flag, __hip_bfloat16* __restrict__ dst) {
  const bool f32 = (*flag != 0);
  const int i = blockIdx.x * 256 + threadIdx.x;   // 0..917503
  const void* src; int off;
  if      (i < 65536)  { src = fcw; off = i; }
  else if (i < 393216) { src = edw; off = i - 65536; }
  else if (i < 589824) { src = wih; off = i - 393216; }
  else if (i < 786432) { src = whh; off = i - 589824; }
  else if (i < 851968) { src = c1w; off = i - 786432; }
  else                 { src = c2w; off = i - 851968; }
  dst[i] = f32 ? f2bf(((const float*)src)[off])
               : ((const __hip_bfloat16*)src)[off];
}

// one-time adj -> internal bf16 (20,971,520 elems), 8 elems/thread
__global__ void adj_cvt(const void* __restrict__ src, const int* __restrict__ flag,
                        __hip_bfloat16* __restrict__ dst) {
  const bool f32 = (*flag != 0);
  const long i = ((long)blockIdx.x * 256 + threadIdx.x) * 8;
  bf16x8 r;
  if (f32) {
    const float* p = (const float*)src + i;
#pragma unroll
    for (int j = 0; j < 8; ++j) r[j] = f2bs(p[j]);
  } else {
    r = *(const bf16x8*)((const __hip_bfloat16*)src + i);
  }
  *(bf16x8*)(dst + i) = r;
}

__global__ void zero_acc(float4* __restrict__ p) {
  p[(long)blockIdx.x * 256 + threadIdx.x] = float4{0.f, 0.f, 0.f, 0.f};
}

// accb = bf16(acc32 + sum_edge_b), 4 elems/thread
__global__ void acc_finish(const float* __restrict__ a32, const float* __restrict__ pool,
                           __hip_bfloat16* __restrict__ out) {
  const long i = ((long)blockIdx.x * 256 + threadIdx.x) * 4;
#pragma unroll
  for (int j = 0; j < 4; ++j)
    out[i + j] = f2bf(a32[i + j] + pool[2304 + ((i + j) & 255)]);
}

// OUT_MODE: 0=bf16 C row-major; 1=fp32 C row-major; 3=bf16 C transposed;
//           4=fp32 atomicAdd (split-K partial)
// A_EXT: A is an external tensor (dtype per *flag); B is always internal bf16.
template<int OUT_MODE, bool HAS_BIAS, bool A_EXT>
__global__ __launch_bounds__(256)
void gemm_bt(const void* __restrict__ A,
             const __hip_bfloat16* __restrict__ Bt,
             const float* __restrict__ bias,
             void* __restrict__ Cp, const int* __restrict__ flag,
             int Kg, int ngrp, int lda, int ldb, int ldc,
             long aBatch, int zdivA, long bBatch, int zdivB, int zmodB,
             long cBatch, int zdivC, long aGrp, long bGrp)
{
  __shared__ __align__(16) __hip_bfloat16 sA[64 * 64];
  __shared__ __align__(16) __hip_bfloat16 sB[64 * 64];
  const bool af32 = A_EXT ? (*flag != 0) : false;
  const int t = threadIdx.x;
  const int w = t >> 6;
  const int l = t & 63;
  const int m0 = blockIdx.x * 64;
  const int n0 = blockIdx.y * 64;
  const int z  = blockIdx.z;

  const long aOff = (long)(z / zdivA) * aBatch;
  const __hip_bfloat16* Bb = Bt + (long)((z / zdivB) % zmodB) * bBatch;

  // staging: 16B chunk p -> LDS(row=p>>3, slot=p&7); slot s of row r holds
  // data chunk s ^ (r&7) (XOR swizzle; SQ_LDS_BANK_CONFLICT measured 0)
  const int p0 = t, p1 = t + 256;
  const int sr0 = p0 >> 3, sc0 = (p0 & 7) ^ (sr0 & 7);
  const int sr1 = p1 >> 3, sc1 = (p1 & 7) ^ (sr1 & 7);

  f32x4 acc[4];
#pragma unroll
  for (int i = 0; i < 4; ++i) acc[i] = (f32x4){0.f, 0.f, 0.f, 0.f};

  const int mrow = w * 16 + (l & 15);
  const int quad = l >> 4;

  for (int g = 0; g < ngrp; ++g) {
    const long aG = aOff + (long)g * aGrp;
    const __hip_bfloat16* Bg = Bb + (long)g * bGrp;
    for (int k0 = 0; k0 < Kg; k0 += 64) {
      bf16x8 a0, a1;
      if (A_EXT) {
        a0 = ld8_ext(A, aG + (long)(m0 + sr0) * lda + (k0 + sc0 * 8), af32);
        a1 = ld8_ext(A, aG + (long)(m0 + sr1) * lda + (k0 + sc1 * 8), af32);
      } else {
        const __hip_bfloat16* Ab = (const __hip_bfloat16*)A;
        a0 = *(const bf16x8*)(Ab + aG + (long)(m0 + sr0) * lda + (k0 + sc0 * 8));
        a1 = *(const bf16x8*)(Ab + aG + (long)(m0 + sr1) * lda + (k0 + sc1 * 8));
      }
      bf16x8 b0 = *(const bf16x8*)(Bg + (long)(n0 + sr0) * ldb + (k0 + sc0 * 8));
      bf16x8 b1 = *(const bf16x8*)(Bg + (long)(n0 + sr1) * ldb + (k0 + sc1 * 8));
      __syncthreads();
      *(bf16x8*)(sA + p0 * 8) = a0;
      *(bf16x8*)(sA + p1 * 8) = a1;
      *(bf16x8*)(sB + p0 * 8) = b0;
      *(bf16x8*)(sB + p1 * 8) = b1;
      __syncthreads();
#pragma unroll
      for (int ks = 0; ks < 2; ++ks) {
        const int cg = ks * 4 + quad;
        bf16x8 af = *(const bf16x8*)(sA + mrow * 64 + ((cg ^ (mrow & 7)) * 8));
#pragma unroll
        for (int t4 = 0; t4 < 4; ++t4) {
          const int nrow = t4 * 16 + (l & 15);
          bf16x8 bfr = *(const bf16x8*)(sB + nrow * 64 + ((cg ^ (nrow & 7)) * 8));
          acc[t4] = __builtin_amdgcn_mfma_f32_16x16x32_bf16(af, bfr, acc[t4], 0, 0, 0);
        }
      }
    }
  }

  // C/D layout: col = lane&15, row = (lane>>4)*4 + reg
#pragma unroll
  for (int t4 = 0; t4 < 4; ++t4) {
    const int n = n0 + t4 * 16 + (l & 15);
    float bv = 0.f;
    if (HAS_BIAS) bv = bias[n];
    if (OUT_MODE == 3) {
      __hip_bfloat16 tmp[4];
#pragma unroll
      for (int r = 0; r < 4; ++r) tmp[r] = f2bf(acc[t4][r] + bv);
      __hip_bfloat16* cb = (__hip_bfloat16*)Cp + (long)z * cBatch +
                           (long)n * ldc + (m0 + w * 16 + quad * 4);
      *(ushort4*)cb = *(const ushort4*)tmp;
    } else if (OUT_MODE == 4) {
      float* cb = (float*)Cp + (long)(z / zdivC) * cBatch;
#pragma unroll
      for (int r = 0; r < 4; ++r) {
        const int m = m0 + w * 16 + quad * 4 + r;
        atomicAdd(cb + (long)m * ldc + n, acc[t4][r]);
      }
    } else {
#pragma unroll
      for (int r = 0; r < 4; ++r) {
        const int m = m0 + w * 16 + quad * 4 + r;
        const float v = acc[t4][r] + bv;
        if (OUT_MODE == 0)
          ((__hip_bfloat16*)Cp)[(long)(z / zdivC) * cBatch + (long)m * ldc + n] = f2bf(v);
        else
          ((float*)Cp)[(long)(z / zdivC) * cBatch + (long)m * ldc + n] = v;
      }
    }
  }
}

// torch GRUCell gates [r,z,n]; h kept bf16 internally
__global__ void gru_gate(const __hip_bfloat16* __restrict__ gi,
                         const __hip_bfloat16* __restrict__ gh,
                         __hip_bfloat16* __restrict__ hbf)
{
  const int m = blockIdx.x;
  const int k = threadIdx.x;
  const long gb = (long)m * 768;
  const float ir = bf2f(gi[gb + k]);
  const float iz = bf2f(gi[gb + 256 + k]);
  const float inn = bf2f(gi[gb + 512 + k]);
  const float hr = bf2f(gh[gb + k]);
  const float hz = bf2f(gh[gb + 256 + k]);
  const float hn = bf2f(gh[gb + 512 + k]);
  const long hidx = (long)m * 256 + k;
  const float h = bf2f(hbf[hidx]);
  const float r = 1.f / (1.f + __expf(-(ir + hr)));
  const float zz = 1.f / (1.f + __expf(-(iz + hz)));
  const float nn = tanhf(inn + r * hn);
  hbf[hidx] = f2bf((1.f - zz) * nn + zz * h);
}

__global__ void epilogue(const float* __restrict__ attnl,
                         const float* __restrict__ featl,
                         const __hip_bfloat16* __restrict__ hbf,
                         float* __restrict__ ge,
                         void* __restrict__ dout, const int* __restrict__ flag)
{
  const bool f32 = (*flag != 0);
  const int b = blockIdx.x;
  const int chunk = blockIdx.y;
  const int k = threadIdx.x;
  __shared__ float red[4];
  float gacc = 0.f;
  for (int i = 0; i < 64; ++i) {
    const int node = chunk * 64 + i;
    const long idx = ((long)b * 1024 + node) * 256 + k;
    const float a = 1.f / (1.f + __expf(-attnl[idx]));
    const float f = tanhf(featl[idx]);
    gacc += a * f;
    if (f32) ((float*)dout)[1024 + idx] = bf2f(hbf[idx]);
    else     ((__hip_bfloat16*)dout)[1024 + idx] = hbf[idx];
    float s = a;
    for (int off = 32; off; off >>= 1) s += __shfl_down(s, off, 64);
    if ((k & 63) == 0) red[k >> 6] = s;
    __syncthreads();
    if (k == 0) {
      const float am = (red[0] + red[1] + red[2] + red[3]) * (1.f / 256.f);
      if (f32) ((float*)dout)[1049600 + b * 1024 + node] = am;
      else     ((__hip_bfloat16*)dout)[1049600 + b * 1024 + node] = f2bf(am);
    }
    __syncthreads();
  }
  atomicAdd(&ge[b * 256 + k], gacc);
}

__global__ void ge_finish(const float* __restrict__ ge, void* __restrict__ dout,
                          const int* __restrict__ flag)
{
  const bool f32 = (*flag != 0);
  const int t = blockIdx.x * 256 + threadIdx.x;
  if (f32) ((float*)dout)[t] = ge[t];
  else     ((__hip_bfloat16*)dout)[t] = f2bf(ge[t]);
}

extern "C" void kernel_launch(void* const* d_in, const int* in_sizes, int n_in,
                              void* d_out, int out_size, void* d_ws, size_t ws_size,
                              hipStream_t stream) {
  (void)in_sizes; (void)n_in; (void)out_size;
  const void* node_f = d_in[0];
  const void* adj    = d_in[1];
  const void* fc_w   = d_in[2];
  const void* fc_b   = d_in[3];
  const void* edge_w = d_in[4];
  const void* edge_b = d_in[5];
  const void* w_ih   = d_in[6];
  const void* w_hh   = d_in[7];
  const void* b_ih   = d_in[8];
  const void* b_hh   = d_in[9];
  const void* c1w    = d_in[10];
  const void* c1b    = d_in[11];
  const void* c2w    = d_in[12];
  const void* c2b    = d_in[13];

  // ws layout:
  //  [0,4) flag | [256,10496) bias pool | [10496,14592) ge
  //  [14592,..) wbf (1.75 MiB) | [1849600,..) hbf (2 MiB)
  //  S=[3946752,..): heT 10M | accb 2M@+10M | acc32 4M@+12M (-> ends ~19.8 MiB)
  //  gi=S[0:6M) gh=S[6:12M) after heT dead; attl/fetl f32 after loop
  //  adjb @ ws+20MiB, 40 MiB (only if ws_size >= 61 MiB)
  char* ws = (char*)d_ws;
  const size_t MB = (size_t)1 << 20;
  int*            flag = (int*)(ws);
  float*          bp   = (float*)(ws + 256);
  float*          ge   = (float*)(ws + 10496);
  __hip_bfloat16* wbf  = (__hip_bfloat16*)(ws + 14592);
  __hip_bfloat16* hbf  = (__hip_bfloat16*)(ws + 1849600);
  char*           S    = ws + 3946752;
  __hip_bfloat16* heT  = (__hip_bfloat16*)(S);
  __hip_bfloat16* accb = (__hip_bfloat16*)(S + 10 * MB);
  float*          acc32= (float*)(S + 12 * MB);
  __hip_bfloat16* gi   = (__hip_bfloat16*)(S);
  __hip_bfloat16* gh   = (__hip_bfloat16*)(S + 6 * MB);
  float*          attl = (float*)(S);
  float*          fetl = (float*)(S + 4 * MB);
  __hip_bfloat16* adjb = (__hip_bfloat16*)(ws + 20 * MB);

  const bool has_adjb  = ws_size >= 61 * MB;  // adjb fits
  const bool has_split = ws_size >= 20 * MB;  // acc32 fits

  detect_dtype<<<1, 256, 0, stream>>>((const uint32_t*)adj, flag);
  prep_pool<<<1, 256, 0, stream>>>(fc_b, b_ih, b_hh, c1b, c2b, edge_b, flag, bp, ge);
  wcvt_all<<<3584, 256, 0, stream>>>(fc_w, edge_w, w_ih, w_hh, c1w, c2w, flag, wbf);
  if (has_adjb) adj_cvt<<<10240, 256, 0, stream>>>(adj, flag, adjb);

  // h = X @ fc_w^T + fc_b
  gemm_bt<0, true, true><<<dim3(64, 4, 1), 256, 0, stream>>>(
      node_f, wbf + 0, bp + 0, hbf, flag,
      256, 1, 256, 256, 256, 0, 1, 0, 1, 1, 0, 1, 0, 0);

  for (int s = 0; s < 5; ++s) {
    // heT[b,e] = (h[b] @ edge_w[e]^T)^T  (z=b*5+e, transposed bf16 store)
    gemm_bt<3, false, false><<<dim3(16, 4, 20), 256, 0, stream>>>(
        hbf, wbf + 65536, nullptr, heT, flag,
        256, 1, 256, 256, 1024,
        (long)1024 * 256, 5, 65536, 1, 5,
        (long)256 * 1024, 1, 0, 0);
    if (has_split) {
      // split-K over edges: acc32[b] += adj[b,e] @ he[b,e]   (atomic fp32)
      zero_acc<<<1024, 256, 0, stream>>>((float4*)acc32);
      if (has_adjb) {
        gemm_bt<4, false, false><<<dim3(16, 4, 20), 256, 0, stream>>>(
            adjb, heT, nullptr, acc32, flag,
            1024, 1, 1024, 1024, 256,
            (long)1024 * 1024, 1, (long)256 * 1024, 1, 20,
            (long)1024 * 256, 5, 0, 0);
      } else {
        gemm_bt<4, false, true><<<dim3(16, 4, 20), 256, 0, stream>>>(
            adj, heT, nullptr, acc32, flag,
            1024, 1, 1024, 1024, 256,
            (long)1024 * 1024, 1, (long)256 * 1024, 1, 20,
            (long)1024 * 256, 5, 0, 0);
      }
      acc_finish<<<1024, 256, 0, stream>>>(acc32, bp, accb);
    } else {
      // fallback: grouped-K (R4 path)
      gemm_bt<0, true, true><<<dim3(16, 4, 4), 256, 0, stream>>>(
          adj, heT, bp + 2304, accb, flag,
          1024, 5, 1024, 1024, 256,
          (long)5 * 1024 * 1024, 1, (long)5 * 256 * 1024, 1, 4,
          (long)1024 * 256, 1, (long)1024 * 1024, (long)256 * 1024);
    }
    // gi = acc @ w_ih^T + b_ih ; gh = h @ w_hh^T + b_hh
    gemm_bt<0, true, false><<<dim3(64, 12, 1), 256, 0, stream>>>(
        accb, wbf + 393216, bp + 256, gi, flag,
        256, 1, 256, 256, 768, 0, 1, 0, 1, 1, 0, 1, 0, 0);
    gemm_bt<0, true, false><<<dim3(64, 12, 1), 256, 0, stream>>>(
        hbf, wbf + 589824, bp + 1024, gh, flag,
        256, 1, 256, 256, 768, 0, 1, 0, 1, 1, 0, 1, 0, 0);
    gru_gate<<<4096, 256, 0, stream>>>(gi, gh, hbf);
  }

  gemm_bt<1, true, false><<<dim3(64, 4, 1), 256, 0, stream>>>(
      hbf, wbf + 786432, bp + 1792, attl, flag,
      256, 1, 256, 256, 256, 0, 1, 0, 1, 1, 0, 1, 0, 0);
  gemm_bt<1, true, false><<<dim3(64, 4, 1), 256, 0, stream>>>(
      hbf, wbf + 851968, bp + 2048, fetl, flag,
      256, 1, 256, 256, 256, 0, 1, 0, 1, 1, 0, 1, 0, 0);

  epilogue<<<dim3(4, 16), 256, 0, stream>>>(attl, fetl, hbf, ge, d_out, flag);
  ge_finish<<<4, 256, 0, stream>>>(ge, d_out, flag);
}

// Round 6
// 579.249 us; speedup vs baseline: 1.5990x; 1.0373x over previous
//
#include <hip/hip_runtime.h>
#include <hip/hip_bf16.h>
#include <cstdint>

// GGNN encoder, B=4, N=1024, DIN=D=256, E=5, STEP=5. Inputs fp32 (sniffed).
// Round 6: epilogue flattened (was 67us @ 2.6% occ); gi/gh and conv1/conv2
// fused into dual dispatches; acc split-K doubled (40 slices, 2560 blocks);
// acc_finish self-zeros; final gru writes node_states directly to d_out.

typedef __attribute__((ext_vector_type(8))) short bf16x8;
typedef __attribute__((ext_vector_type(4))) float f32x4;

__device__ __forceinline__ float bf2f(__hip_bfloat16 x) { return __bfloat162float(x); }
__device__ __forceinline__ __hip_bfloat16 f2bf(float x) { return __float2bfloat16(x); }
__device__ __forceinline__ short f2bs(float x) {
  __hip_bfloat16 h = __float2bfloat16(x);
  return *reinterpret_cast<short*>(&h);
}

__device__ __forceinline__ bf16x8 ld8_ext(const void* base, long off, bool f32) {
  if (f32) {
    const float* p = (const float*)base + off;
    bf16x8 r;
#pragma unroll
    for (int i = 0; i < 8; ++i) r[i] = f2bs(p[i]);
    return r;
  }
  return *(const bf16x8*)((const __hip_bfloat16*)base + off);
}

// ---- dtype sniffer: flag = 1 if inputs are fp32, 0 if bf16 ----
__global__ void detect_dtype(const uint32_t* __restrict__ raw, int* __restrict__ flag) {
  __shared__ int cnt;
  if (threadIdx.x == 0) cnt = 0;
  __syncthreads();
  int c = 0;
  for (int i = threadIdx.x; i < 512; i += 256) {
    uint32_t byte = (raw[i] >> 8) & 0xFF;
    if (byte >= 0x28 && byte <= 0x40) ++c;
  }
  atomicAdd(&cnt, c);
  __syncthreads();
  if (threadIdx.x == 0) *flag = (cnt < 300) ? 1 : 0;
}

// fp32 bias pool: [0:256) fc_b | [256:1024) b_ih | [1024:1792) b_hh |
// [1792:2048) conv1_b | [2048:2304) conv2_b | [2304:2560) sum_e edge_b
__global__ void prep_pool(const void* fcb, const void* bih, const void* bhh,
                          const void* c1b, const void* c2b, const void* edgeb,
                          const int* __restrict__ flag,
                          float* __restrict__ pool, float* __restrict__ ge) {
  const bool f32 = (*flag != 0);
  for (int t = threadIdx.x; t < 2560; t += 256) {
    const void* p; int i;
    if (t < 256)       { p = fcb;  i = t; }
    else if (t < 1024) { p = bih;  i = t - 256; }
    else if (t < 1792) { p = bhh;  i = t - 1024; }
    else if (t < 2048) { p = c1b;  i = t - 1792; }
    else if (t < 2304) { p = c2b;  i = t - 2048; }
    else {
      int k = t - 2304; float s = 0.f;
      for (int e = 0; e < 5; ++e)
        s += f32 ? ((const float*)edgeb)[e * 256 + k]
                 : bf2f(((const __hip_bfloat16*)edgeb)[e * 256 + k]);
      pool[t] = s; continue;
    }
    pool[t] = f32 ? ((const float*)p)[i] : bf2f(((const __hip_bfloat16*)p)[i]);
  }
  for (int t = threadIdx.x; t < 1024; t += 256) ge[t] = 0.f;
}

// ingest all 6 weight matrices into one internal bf16 pool
__global__ void wcvt_all(const void* fcw, const void* edw, const void* wih,
                         const void* whh, const void* c1w, const void* c2w,
                         const int* __restrict__ flag, __hip_bfloat16* __restrict__ dst) {
  const bool f32 = (*flag != 0);
  const int i = blockIdx.x * 256 + threadIdx.x;   // 0..917503
  const void* src; int off;
  if      (i < 65536)  { src = fcw; off = i; }
  else if (i < 393216) { src = edw; off = i - 65536; }
  else if (i < 589824) { src = wih; off = i - 393216; }
  else if (i < 786432) { src = whh; off = i - 589824; }
  else if (i < 851968) { src = c1w; off = i - 786432; }
  else                 { src = c2w; off = i - 851968; }
  dst[i] = f32 ? f2bf(((const float*)src)[off])
               : ((const __hip_bfloat16*)src)[off];
}

// one-time adj -> internal bf16 (20,971,520 elems), 8 elems/thread
__global__ void adj_cvt(const void* __restrict__ src, const int* __restrict__ flag,
                        __hip_bfloat16* __restrict__ dst) {
  const bool f32 = (*flag != 0);
  const long i = ((long)blockIdx.x * 256 + threadIdx.x) * 8;
  bf16x8 r;
  if (f32) {
    const float* p = (const float*)src + i;
#pragma unroll
    for (int j = 0; j < 8; ++j) r[j] = f2bs(p[j]);
  } else {
    r = *(const bf16x8*)((const __hip_bfloat16*)src + i);
  }
  *(bf16x8*)(dst + i) = r;
}

__global__ void zero_acc(float4* __restrict__ p) {
  p[(long)blockIdx.x * 256 + threadIdx.x] = float4{0.f, 0.f, 0.f, 0.f};
}

// accb = bf16(acc32 + sum_edge_b); also re-zeros acc32 for the next step
__global__ void acc_finish(float* __restrict__ a32, const float* __restrict__ pool,
                           __hip_bfloat16* __restrict__ out) {
  const long i = ((long)blockIdx.x * 256 + threadIdx.x) * 4;
#pragma unroll
  for (int j = 0; j < 4; ++j) {
    out[i + j] = f2bf(a32[i + j] + pool[2304 + ((i + j) & 255)]);
    a32[i + j] = 0.f;
  }
}

// OUT_MODE: 0=bf16 C row-major; 1=fp32 C row-major; 3=bf16 C transposed;
//           4=fp32 atomicAdd (split-K partial)
// A_EXT: A is external (dtype per *flag). DUAL: z>=zSplit switches A/B/C/bias.
template<int OUT_MODE, bool HAS_BIAS, bool A_EXT, bool DUAL>
__global__ __launch_bounds__(256)
void gemm_bt(const void* __restrict__ A, const __hip_bfloat16* __restrict__ Bt,
             const float* __restrict__ bias, void* __restrict__ Cp,
             const void* __restrict__ A2, const __hip_bfloat16* __restrict__ Bt2,
             const float* __restrict__ bias2, void* __restrict__ Cp2,
             const int* __restrict__ flag,
             int Kg, int ngrp, int lda, int ldb, int ldc,
             long aBatch, int zdivA, long bBatch, int zdivB, int zmodB,
             long cBatch, int zdivC, long aGrp, long bGrp,
             int zSplit, int kSplit)
{
  __shared__ __align__(16) __hip_bfloat16 sA[64 * 64];
  __shared__ __align__(16) __hip_bfloat16 sB[64 * 64];
  const bool af32 = A_EXT ? (*flag != 0) : false;
  const int t = threadIdx.x;
  const int w = t >> 6;
  const int l = t & 63;
  const int m0 = blockIdx.x * 64;
  const int n0 = blockIdx.y * 64;
  int z = blockIdx.z;

  const void* Au = A; const __hip_bfloat16* Btu = Bt;
  const float* biasu = bias; void* Cpu = Cp;
  if (DUAL && z >= zSplit) { Au = A2; Btu = Bt2; biasu = bias2; Cpu = Cp2; z -= zSplit; }
  const int zs = z / kSplit;
  const int kb = (z - zs * kSplit) * Kg;   // K offset of this split slice

  const long aOff = (long)(zs / zdivA) * aBatch + kb;
  const __hip_bfloat16* Bb = Btu + (long)((zs / zdivB) % zmodB) * bBatch + kb;

  // staging: 16B chunk p -> LDS(row=p>>3, slot=p&7); slot s of row r holds
  // data chunk s ^ (r&7) (XOR swizzle; SQ_LDS_BANK_CONFLICT measured 0)
  const int p0 = t, p1 = t + 256;
  const int sr0 = p0 >> 3, sc0 = (p0 & 7) ^ (sr0 & 7);
  const int sr1 = p1 >> 3, sc1 = (p1 & 7) ^ (sr1 & 7);

  f32x4 acc[4];
#pragma unroll
  for (int i = 0; i < 4; ++i) acc[i] = (f32x4){0.f, 0.f, 0.f, 0.f};

  const int mrow = w * 16 + (l & 15);
  const int quad = l >> 4;

  for (int g = 0; g < ngrp; ++g) {
    const long aG = aOff + (long)g * aGrp;
    const __hip_bfloat16* Bg = Bb + (long)g * bGrp;
    for (int k0 = 0; k0 < Kg; k0 += 64) {
      bf16x8 a0, a1;
      if (A_EXT) {
        a0 = ld8_ext(Au, aG + (long)(m0 + sr0) * lda + (k0 + sc0 * 8), af32);
        a1 = ld8_ext(Au, aG + (long)(m0 + sr1) * lda + (k0 + sc1 * 8), af32);
      } else {
        const __hip_bfloat16* Ab = (const __hip_bfloat16*)Au;
        a0 = *(const bf16x8*)(Ab + aG + (long)(m0 + sr0) * lda + (k0 + sc0 * 8));
        a1 = *(const bf16x8*)(Ab + aG + (long)(m0 + sr1) * lda + (k0 + sc1 * 8));
      }
      bf16x8 b0 = *(const bf16x8*)(Bg + (long)(n0 + sr0) * ldb + (k0 + sc0 * 8));
      bf16x8 b1 = *(const bf16x8*)(Bg + (long)(n0 + sr1) * ldb + (k0 + sc1 * 8));
      __syncthreads();
      *(bf16x8*)(sA + p0 * 8) = a0;
      *(bf16x8*)(sA + p1 * 8) = a1;
      *(bf16x8*)(sB + p0 * 8) = b0;
      *(bf16x8*)(sB + p1 * 8) = b1;
      __syncthreads();
#pragma unroll
      for (int ks = 0; ks < 2; ++ks) {
        const int cg = ks * 4 + quad;
        bf16x8 af = *(const bf16x8*)(sA + mrow * 64 + ((cg ^ (mrow & 7)) * 8));
#pragma unroll
        for (int t4 = 0; t4 < 4; ++t4) {
          const int nrow = t4 * 16 + (l & 15);
          bf16x8 bfr = *(const bf16x8*)(sB + nrow * 64 + ((cg ^ (nrow & 7)) * 8));
          acc[t4] = __builtin_amdgcn_mfma_f32_16x16x32_bf16(af, bfr, acc[t4], 0, 0, 0);
        }
      }
    }
  }

  // C/D layout: col = lane&15, row = (lane>>4)*4 + reg
#pragma unroll
  for (int t4 = 0; t4 < 4; ++t4) {
    const int n = n0 + t4 * 16 + (l & 15);
    float bv = 0.f;
    if (HAS_BIAS) bv = biasu[n];
    if (OUT_MODE == 3) {
      __hip_bfloat16 tmp[4];
#pragma unroll
      for (int r = 0; r < 4; ++r) tmp[r] = f2bf(acc[t4][r] + bv);
      __hip_bfloat16* cb = (__hip_bfloat16*)Cpu + (long)zs * cBatch +
                           (long)n * ldc + (m0 + w * 16 + quad * 4);
      *(ushort4*)cb = *(const ushort4*)tmp;
    } else if (OUT_MODE == 4) {
      float* cb = (float*)Cpu + (long)(zs / zdivC) * cBatch;
#pragma unroll
      for (int r = 0; r < 4; ++r) {
        const int m = m0 + w * 16 + quad * 4 + r;
        atomicAdd(cb + (long)m * ldc + n, acc[t4][r]);
      }
    } else {
#pragma unroll
      for (int r = 0; r < 4; ++r) {
        const int m = m0 + w * 16 + quad * 4 + r;
        const float v = acc[t4][r] + bv;
        if (OUT_MODE == 0)
          ((__hip_bfloat16*)Cpu)[(long)(zs / zdivC) * cBatch + (long)m * ldc + n] = f2bf(v);
        else
          ((float*)Cpu)[(long)(zs / zdivC) * cBatch + (long)m * ldc + n] = v;
      }
    }
  }
}

// torch GRUCell gates [r,z,n]; final step also writes node_states to d_out
__global__ void gru_gate(const __hip_bfloat16* __restrict__ gi,
                         const __hip_bfloat16* __restrict__ gh,
                         __hip_bfloat16* __restrict__ hbf,
                         void* __restrict__ ns_out, const int* __restrict__ flag)
{
  const int m = blockIdx.x;
  const int k = threadIdx.x;
  const long gb = (long)m * 768;
  const float ir = bf2f(gi[gb + k]);
  const float iz = bf2f(gi[gb + 256 + k]);
  const float inn = bf2f(gi[gb + 512 + k]);
  const float hr = bf2f(gh[gb + k]);
  const float hz = bf2f(gh[gb + 256 + k]);
  const float hn = bf2f(gh[gb + 512 + k]);
  const long hidx = (long)m * 256 + k;
  const float h = bf2f(hbf[hidx]);
  const float r = 1.f / (1.f + __expf(-(ir + hr)));
  const float zz = 1.f / (1.f + __expf(-(iz + hz)));
  const float nn = tanhf(inn + r * hn);
  const float hnew = (1.f - zz) * nn + zz * h;
  const __hip_bfloat16 hb = f2bf(hnew);
  hbf[hidx] = hb;
  if (ns_out) {
    if (*flag) ((float*)ns_out)[1024 + hidx] = hnew;
    else       ((__hip_bfloat16*)ns_out)[1024 + hidx] = hb;
  }
}

// ge partial: grid (128, 4); thread k accumulates a*f over 8 nodes, 1 atomic.
__global__ void ge_partial(const float* __restrict__ attnl,
                           const float* __restrict__ featl,
                           float* __restrict__ ge)
{
  const int b = blockIdx.y;
  const int k = threadIdx.x;
  float gacc = 0.f;
  for (int i = 0; i < 8; ++i) {
    const int node = blockIdx.x * 8 + i;
    const long idx = ((long)b * 1024 + node) * 256 + k;
    const float a = 1.f / (1.f + __expf(-attnl[idx]));
    const float f = tanhf(featl[idx]);
    gacc += a * f;
  }
  atomicAdd(&ge[b * 256 + k], gacc);
}

// attn_map: one wave per node; float4 loads + shuffle reduce.
__global__ void attn_map_k(const float* __restrict__ attnl,
                           void* __restrict__ dout, const int* __restrict__ flag)
{
  const int node = blockIdx.x * 4 + (threadIdx.x >> 6);   // 0..4095 (b*1024+n)
  const int l = threadIdx.x & 63;
  const float4 v = *((const float4*)attnl + (long)node * 64 + l);
  float s = 1.f / (1.f + __expf(-v.x)) + 1.f / (1.f + __expf(-v.y)) +
            1.f / (1.f + __expf(-v.z)) + 1.f / (1.f + __expf(-v.w));
  for (int off = 32; off; off >>= 1) s += __shfl_down(s, off, 64);
  if (l == 0) {
    const float am = s * (1.f / 256.f);
    if (*flag) ((float*)dout)[1049600 + node] = am;
    else       ((__hip_bfloat16*)dout)[1049600 + node] = f2bf(am);
  }
}

__global__ void ge_finish(const float* __restrict__ ge, void* __restrict__ dout,
                          const int* __restrict__ flag)
{
  const int t = blockIdx.x * 256 + threadIdx.x;
  if (*flag) ((float*)dout)[t] = ge[t];
  else       ((__hip_bfloat16*)dout)[t] = f2bf(ge[t]);
}

extern "C" void kernel_launch(void* const* d_in, const int* in_sizes, int n_in,
                              void* d_out, int out_size, void* d_ws, size_t ws_size,
                              hipStream_t stream) {
  (void)in_sizes; (void)n_in; (void)out_size;
  const void* node_f = d_in[0];
  const void* adj    = d_in[1];
  const void* fc_w   = d_in[2];
  const void* fc_b   = d_in[3];
  const void* edge_w = d_in[4];
  const void* edge_b = d_in[5];
  const void* w_ih   = d_in[6];
  const void* w_hh   = d_in[7];
  const void* b_ih   = d_in[8];
  const void* b_hh   = d_in[9];
  const void* c1w    = d_in[10];
  const void* c1b    = d_in[11];
  const void* c2w    = d_in[12];
  const void* c2b    = d_in[13];

  char* ws = (char*)d_ws;
  const size_t MB = (size_t)1 << 20;
  int*            flag = (int*)(ws);
  float*          bp   = (float*)(ws + 256);
  float*          ge   = (float*)(ws + 10496);
  __hip_bfloat16* wbf  = (__hip_bfloat16*)(ws + 14592);
  __hip_bfloat16* hbf  = (__hip_bfloat16*)(ws + 1849600);
  char*           S    = ws + 3946752;
  __hip_bfloat16* heT  = (__hip_bfloat16*)(S);
  __hip_bfloat16* accb = (__hip_bfloat16*)(S + 10 * MB);
  float*          acc32= (float*)(S + 12 * MB);
  __hip_bfloat16* gi   = (__hip_bfloat16*)(S);
  __hip_bfloat16* gh   = (__hip_bfloat16*)(S + 6 * MB);
  float*          attl = (float*)(S);
  float*          fetl = (float*)(S + 4 * MB);
  __hip_bfloat16* adjb = (__hip_bfloat16*)(ws + 20 * MB);

  const bool has_adjb  = ws_size >= 61 * MB;
  const bool has_split = ws_size >= 20 * MB;

  detect_dtype<<<1, 256, 0, stream>>>((const uint32_t*)adj, flag);
  prep_pool<<<1, 256, 0, stream>>>(fc_b, b_ih, b_hh, c1b, c2b, edge_b, flag, bp, ge);
  wcvt_all<<<3584, 256, 0, stream>>>(fc_w, edge_w, w_ih, w_hh, c1w, c2w, flag, wbf);
  if (has_adjb) adj_cvt<<<10240, 256, 0, stream>>>(adj, flag, adjb);
  if (has_split) zero_acc<<<1024, 256, 0, stream>>>((float4*)acc32);

  // h = X @ fc_w^T + fc_b
  gemm_bt<0, true, true, false><<<dim3(64, 4, 1), 256, 0, stream>>>(
      node_f, wbf + 0, bp + 0, hbf, nullptr, nullptr, nullptr, nullptr, flag,
      256, 1, 256, 256, 256, 0, 1, 0, 1, 1, 0, 1, 0, 0, 0, 1);

  for (int s = 0; s < 5; ++s) {
    // heT[b,e] = (h[b] @ edge_w[e]^T)^T
    gemm_bt<3, false, false, false><<<dim3(16, 4, 20), 256, 0, stream>>>(
        hbf, wbf + 65536, nullptr, heT, nullptr, nullptr, nullptr, nullptr, flag,
        256, 1, 256, 256, 1024,
        (long)1024 * 256, 5, 65536, 1, 5,
        (long)256 * 1024, 1, 0, 0, 0, 1);
    if (has_split) {
      // acc32[b] += adj[b,e] @ he[b,e], K split in 2 (z = (b*5+e)*2 + half)
      if (has_adjb) {
        gemm_bt<4, false, false, false><<<dim3(16, 4, 40), 256, 0, stream>>>(
            adjb, heT, nullptr, acc32, nullptr, nullptr, nullptr, nullptr, flag,
            512, 1, 1024, 1024, 256,
            (long)1024 * 1024, 1, (long)256 * 1024, 1, 20,
            (long)1024 * 256, 5, 0, 0, 0, 2);
      } else {
        gemm_bt<4, false, true, false><<<dim3(16, 4, 40), 256, 0, stream>>>(
            adj, heT, nullptr, acc32, nullptr, nullptr, nullptr, nullptr, flag,
            512, 1, 1024, 1024, 256,
            (long)1024 * 1024, 1, (long)256 * 1024, 1, 20,
            (long)1024 * 256, 5, 0, 0, 0, 2);
      }
      acc_finish<<<1024, 256, 0, stream>>>(acc32, bp, accb);
    } else {
      gemm_bt<0, true, true, false><<<dim3(16, 4, 4), 256, 0, stream>>>(
          adj, heT, bp + 2304, accb, nullptr, nullptr, nullptr, nullptr, flag,
          1024, 5, 1024, 1024, 256,
          (long)5 * 1024 * 1024, 1, (long)5 * 256 * 1024, 1, 4,
          (long)1024 * 256, 1, (long)1024 * 1024, (long)256 * 1024, 0, 1);
    }
    // gi = acc @ w_ih^T + b_ih  AND  gh = h @ w_hh^T + b_hh  (dual dispatch)
    gemm_bt<0, true, false, true><<<dim3(64, 12, 2), 256, 0, stream>>>(
        accb, wbf + 393216, bp + 256, gi,
        hbf,  wbf + 589824, bp + 1024, gh, flag,
        256, 1, 256, 256, 768, 0, 1, 0, 1, 1, 0, 1, 0, 0, 1, 1);
    gru_gate<<<4096, 256, 0, stream>>>(gi, gh, hbf,
                                       (s == 4) ? d_out : nullptr, flag);
  }

  // attn/feat logits in one dual dispatch (fp32 out)
  gemm_bt<1, true, false, true><<<dim3(64, 4, 2), 256, 0, stream>>>(
      hbf, wbf + 786432, bp + 1792, attl,
      hbf, wbf + 851968, bp + 2048, fetl, flag,
      256, 1, 256, 256, 256, 0, 1, 0, 1, 1, 0, 1, 0, 0, 1, 1);

  ge_partial<<<dim3(128, 4), 256, 0, stream>>>(attl, fetl, ge);
  attn_map_k<<<1024, 256, 0, stream>>>(attl, d_out, flag);
  ge_finish<<<4, 256, 0, stream>>>(ge, d_out, flag);
}

// Round 7
// 461.349 us; speedup vs baseline: 2.0076x; 1.2556x over previous
//
#include <hip/hip_runtime.h>
#include <hip/hip_bf16.h>
#include <cstdint>

// GGNN encoder, B=4, N=1024, DIN=D=256, E=5, STEP=5. Inputs fp32 (sniffed).
// Round 7: heT computed as edge_w @ h^T (row-major coalesced stores, no
// transposed scatter); acc split over e writes plain fp32 partials (no
// atomics, no zero pass); acc_finish reduces 5 slices + bias.

typedef __attribute__((ext_vector_type(8))) short bf16x8;
typedef __attribute__((ext_vector_type(4))) float f32x4;

__device__ __forceinline__ float bf2f(__hip_bfloat16 x) { return __bfloat162float(x); }
__device__ __forceinline__ __hip_bfloat16 f2bf(float x) { return __float2bfloat16(x); }
__device__ __forceinline__ short f2bs(float x) {
  __hip_bfloat16 h = __float2bfloat16(x);
  return *reinterpret_cast<short*>(&h);
}

__device__ __forceinline__ bf16x8 ld8_ext(const void* base, long off, bool f32) {
  if (f32) {
    const float* p = (const float*)base + off;
    bf16x8 r;
#pragma unroll
    for (int i = 0; i < 8; ++i) r[i] = f2bs(p[i]);
    return r;
  }
  return *(const bf16x8*)((const __hip_bfloat16*)base + off);
}

// ---- dtype sniffer: flag = 1 if inputs are fp32, 0 if bf16 ----
__global__ void detect_dtype(const uint32_t* __restrict__ raw, int* __restrict__ flag) {
  __shared__ int cnt;
  if (threadIdx.x == 0) cnt = 0;
  __syncthreads();
  int c = 0;
  for (int i = threadIdx.x; i < 512; i += 256) {
    uint32_t byte = (raw[i] >> 8) & 0xFF;
    if (byte >= 0x28 && byte <= 0x40) ++c;
  }
  atomicAdd(&cnt, c);
  __syncthreads();
  if (threadIdx.x == 0) *flag = (cnt < 300) ? 1 : 0;
}

// fp32 bias pool: [0:256) fc_b | [256:1024) b_ih | [1024:1792) b_hh |
// [1792:2048) conv1_b | [2048:2304) conv2_b | [2304:2560) sum_e edge_b
__global__ void prep_pool(const void* fcb, const void* bih, const void* bhh,
                          const void* c1b, const void* c2b, const void* edgeb,
                          const int* __restrict__ flag,
                          float* __restrict__ pool, float* __restrict__ ge) {
  const bool f32 = (*flag != 0);
  for (int t = threadIdx.x; t < 2560; t += 256) {
    const void* p; int i;
    if (t < 256)       { p = fcb;  i = t; }
    else if (t < 1024) { p = bih;  i = t - 256; }
    else if (t < 1792) { p = bhh;  i = t - 1024; }
    else if (t < 2048) { p = c1b;  i = t - 1792; }
    else if (t < 2304) { p = c2b;  i = t - 2048; }
    else {
      int k = t - 2304; float s = 0.f;
      for (int e = 0; e < 5; ++e)
        s += f32 ? ((const float*)edgeb)[e * 256 + k]
                 : bf2f(((const __hip_bfloat16*)edgeb)[e * 256 + k]);
      pool[t] = s; continue;
    }
    pool[t] = f32 ? ((const float*)p)[i] : bf2f(((const __hip_bfloat16*)p)[i]);
  }
  for (int t = threadIdx.x; t < 1024; t += 256) ge[t] = 0.f;
}

// ingest all 6 weight matrices into one internal bf16 pool
__global__ void wcvt_all(const void* fcw, const void* edw, const void* wih,
                         const void* whh, const void* c1w, const void* c2w,
                         const int* __restrict__ flag, __hip_bfloat16* __restrict__ dst) {
  const bool f32 = (*flag != 0);
  const int i = blockIdx.x * 256 + threadIdx.x;   // 0..917503
  const void* src; int off;
  if      (i < 65536)  { src = fcw; off = i; }
  else if (i < 393216) { src = edw; off = i - 65536; }
  else if (i < 589824) { src = wih; off = i - 393216; }
  else if (i < 786432) { src = whh; off = i - 589824; }
  else if (i < 851968) { src = c1w; off = i - 786432; }
  else                 { src = c2w; off = i - 851968; }
  dst[i] = f32 ? f2bf(((const float*)src)[off])
               : ((const __hip_bfloat16*)src)[off];
}

// one-time adj -> internal bf16 (20,971,520 elems), 8 elems/thread
__global__ void adj_cvt(const void* __restrict__ src, const int* __restrict__ flag,
                        __hip_bfloat16* __restrict__ dst) {
  const bool f32 = (*flag != 0);
  const long i = ((long)blockIdx.x * 256 + threadIdx.x) * 8;
  bf16x8 r;
  if (f32) {
    const float* p = (const float*)src + i;
#pragma unroll
    for (int j = 0; j < 8; ++j) r[j] = f2bs(p[j]);
  } else {
    r = *(const bf16x8*)((const __hip_bfloat16*)src + i);
  }
  *(bf16x8*)(dst + i) = r;
}

// accb = bf16(sum_e partials[b,e] + sum_edge_b)
__global__ void acc_finish(const float* __restrict__ p, const float* __restrict__ pool,
                           __hip_bfloat16* __restrict__ out) {
  const long i = (long)blockIdx.x * 256 + threadIdx.x;  // 0..2^20-1
  const int b = (int)(i >> 18);
  const long base = (long)b * 5 * 262144 + (i & 262143);
  float s = pool[2304 + (i & 255)];
#pragma unroll
  for (int e = 0; e < 5; ++e) s += p[base + (long)e * 262144];
  out[i] = f2bf(s);
}

// OUT_MODE: 0=bf16 C row-major; 1=fp32 C row-major
// A_EXT: A is external (dtype per *flag). DUAL: z>=zSplit switches A/B/C/bias.
template<int OUT_MODE, bool HAS_BIAS, bool A_EXT, bool DUAL>
__global__ __launch_bounds__(256)
void gemm_bt(const void* __restrict__ A, const __hip_bfloat16* __restrict__ Bt,
             const float* __restrict__ bias, void* __restrict__ Cp,
             const void* __restrict__ A2, const __hip_bfloat16* __restrict__ Bt2,
             const float* __restrict__ bias2, void* __restrict__ Cp2,
             const int* __restrict__ flag,
             int Kg, int ngrp, int lda, int ldb, int ldc,
             long aBatch, int zdivA, int zmodA,
             long bBatch, int zdivB, int zmodB,
             long cBatch, int zdivC, long aGrp, long bGrp, int zSplit)
{
  __shared__ __align__(16) __hip_bfloat16 sA[64 * 64];
  __shared__ __align__(16) __hip_bfloat16 sB[64 * 64];
  const bool af32 = A_EXT ? (*flag != 0) : false;
  const int t = threadIdx.x;
  const int w = t >> 6;
  const int l = t & 63;
  const int m0 = blockIdx.x * 64;
  const int n0 = blockIdx.y * 64;
  int z = blockIdx.z;

  const void* Au = A; const __hip_bfloat16* Btu = Bt;
  const float* biasu = bias; void* Cpu = Cp;
  if (DUAL && z >= zSplit) { Au = A2; Btu = Bt2; biasu = bias2; Cpu = Cp2; z -= zSplit; }

  const long aOff = (long)((z / zdivA) % zmodA) * aBatch;
  const __hip_bfloat16* Bb = Btu + (long)((z / zdivB) % zmodB) * bBatch;

  // staging: 16B chunk p -> LDS(row=p>>3, slot=p&7); slot s of row r holds
  // data chunk s ^ (r&7) (XOR swizzle; SQ_LDS_BANK_CONFLICT measured 0)
  const int p0 = t, p1 = t + 256;
  const int sr0 = p0 >> 3, sc0 = (p0 & 7) ^ (sr0 & 7);
  const int sr1 = p1 >> 3, sc1 = (p1 & 7) ^ (sr1 & 7);

  f32x4 acc[4];
#pragma unroll
  for (int i = 0; i < 4; ++i) acc[i] = (f32x4){0.f, 0.f, 0.f, 0.f};

  const int mrow = w * 16 + (l & 15);
  const int quad = l >> 4;

  for (int g = 0; g < ngrp; ++g) {
    const long aG = aOff + (long)g * aGrp;
    const __hip_bfloat16* Bg = Bb + (long)g * bGrp;
    for (int k0 = 0; k0 < Kg; k0 += 64) {
      bf16x8 a0, a1;
      if (A_EXT) {
        a0 = ld8_ext(Au, aG + (long)(m0 + sr0) * lda + (k0 + sc0 * 8), af32);
        a1 = ld8_ext(Au, aG + (long)(m0 + sr1) * lda + (k0 + sc1 * 8), af32);
      } else {
        const __hip_bfloat16* Ab = (const __hip_bfloat16*)Au;
        a0 = *(const bf16x8*)(Ab + aG + (long)(m0 + sr0) * lda + (k0 + sc0 * 8));
        a1 = *(const bf16x8*)(Ab + aG + (long)(m0 + sr1) * lda + (k0 + sc1 * 8));
      }
      bf16x8 b0 = *(const bf16x8*)(Bg + (long)(n0 + sr0) * ldb + (k0 + sc0 * 8));
      bf16x8 b1 = *(const bf16x8*)(Bg + (long)(n0 + sr1) * ldb + (k0 + sc1 * 8));
      __syncthreads();
      *(bf16x8*)(sA + p0 * 8) = a0;
      *(bf16x8*)(sA + p1 * 8) = a1;
      *(bf16x8*)(sB + p0 * 8) = b0;
      *(bf16x8*)(sB + p1 * 8) = b1;
      __syncthreads();
#pragma unroll
      for (int ks = 0; ks < 2; ++ks) {
        const int cg = ks * 4 + quad;
        bf16x8 af = *(const bf16x8*)(sA + mrow * 64 + ((cg ^ (mrow & 7)) * 8));
#pragma unroll
        for (int t4 = 0; t4 < 4; ++t4) {
          const int nrow = t4 * 16 + (l & 15);
          bf16x8 bfr = *(const bf16x8*)(sB + nrow * 64 + ((cg ^ (nrow & 7)) * 8));
          acc[t4] = __builtin_amdgcn_mfma_f32_16x16x32_bf16(af, bfr, acc[t4], 0, 0, 0);
        }
      }
    }
  }

  // C/D layout: col = lane&15, row = (lane>>4)*4 + reg
  const long cOff = (long)(z / zdivC) * cBatch;
#pragma unroll
  for (int t4 = 0; t4 < 4; ++t4) {
    const int n = n0 + t4 * 16 + (l & 15);
    float bv = 0.f;
    if (HAS_BIAS) bv = biasu[n];
#pragma unroll
    for (int r = 0; r < 4; ++r) {
      const int m = m0 + w * 16 + quad * 4 + r;
      const float v = acc[t4][r] + bv;
      if (OUT_MODE == 0)
        ((__hip_bfloat16*)Cpu)[cOff + (long)m * ldc + n] = f2bf(v);
      else
        ((float*)Cpu)[cOff + (long)m * ldc + n] = v;
    }
  }
}

// torch GRUCell gates [r,z,n]; final step also writes node_states to d_out
__global__ void gru_gate(const __hip_bfloat16* __restrict__ gi,
                         const __hip_bfloat16* __restrict__ gh,
                         __hip_bfloat16* __restrict__ hbf,
                         void* __restrict__ ns_out, const int* __restrict__ flag)
{
  const int m = blockIdx.x;
  const int k = threadIdx.x;
  const long gb = (long)m * 768;
  const float ir = bf2f(gi[gb + k]);
  const float iz = bf2f(gi[gb + 256 + k]);
  const float inn = bf2f(gi[gb + 512 + k]);
  const float hr = bf2f(gh[gb + k]);
  const float hz = bf2f(gh[gb + 256 + k]);
  const float hn = bf2f(gh[gb + 512 + k]);
  const long hidx = (long)m * 256 + k;
  const float h = bf2f(hbf[hidx]);
  const float r = 1.f / (1.f + __expf(-(ir + hr)));
  const float zz = 1.f / (1.f + __expf(-(iz + hz)));
  const float nn = tanhf(inn + r * hn);
  const float hnew = (1.f - zz) * nn + zz * h;
  const __hip_bfloat16 hb = f2bf(hnew);
  hbf[hidx] = hb;
  if (ns_out) {
    if (*flag) ((float*)ns_out)[1024 + hidx] = hnew;
    else       ((__hip_bfloat16*)ns_out)[1024 + hidx] = hb;
  }
}

// ge partial: grid (128, 4); thread k accumulates a*f over 8 nodes, 1 atomic.
__global__ void ge_partial(const float* __restrict__ attnl,
                           const float* __restrict__ featl,
                           float* __restrict__ ge)
{
  const int b = blockIdx.y;
  const int k = threadIdx.x;
  float gacc = 0.f;
  for (int i = 0; i < 8; ++i) {
    const int node = blockIdx.x * 8 + i;
    const long idx = ((long)b * 1024 + node) * 256 + k;
    const float a = 1.f / (1.f + __expf(-attnl[idx]));
    const float f = tanhf(featl[idx]);
    gacc += a * f;
  }
  atomicAdd(&ge[b * 256 + k], gacc);
}

// attn_map: one wave per node; float4 loads + shuffle reduce.
__global__ void attn_map_k(const float* __restrict__ attnl,
                           void* __restrict__ dout, const int* __restrict__ flag)
{
  const int node = blockIdx.x * 4 + (threadIdx.x >> 6);   // 0..4095 (b*1024+n)
  const int l = threadIdx.x & 63;
  const float4 v = *((const float4*)attnl + (long)node * 64 + l);
  float s = 1.f / (1.f + __expf(-v.x)) + 1.f / (1.f + __expf(-v.y)) +
            1.f / (1.f + __expf(-v.z)) + 1.f / (1.f + __expf(-v.w));
  for (int off = 32; off; off >>= 1) s += __shfl_down(s, off, 64);
  if (l == 0) {
    const float am = s * (1.f / 256.f);
    if (*flag) ((float*)dout)[1049600 + node] = am;
    else       ((__hip_bfloat16*)dout)[1049600 + node] = f2bf(am);
  }
}

__global__ void ge_finish(const float* __restrict__ ge, void* __restrict__ dout,
                          const int* __restrict__ flag)
{
  const int t = blockIdx.x * 256 + threadIdx.x;
  if (*flag) ((float*)dout)[t] = ge[t];
  else       ((__hip_bfloat16*)dout)[t] = f2bf(ge[t]);
}

extern "C" void kernel_launch(void* const* d_in, const int* in_sizes, int n_in,
                              void* d_out, int out_size, void* d_ws, size_t ws_size,
                              hipStream_t stream) {
  (void)in_sizes; (void)n_in; (void)out_size;
  const void* node_f = d_in[0];
  const void* adj    = d_in[1];
  const void* fc_w   = d_in[2];
  const void* fc_b   = d_in[3];
  const void* edge_w = d_in[4];
  const void* edge_b = d_in[5];
  const void* w_ih   = d_in[6];
  const void* w_hh   = d_in[7];
  const void* b_ih   = d_in[8];
  const void* b_hh   = d_in[9];
  const void* c1w    = d_in[10];
  const void* c1b    = d_in[11];
  const void* c2w    = d_in[12];
  const void* c2b    = d_in[13];

  // ws layout (fill profile shows ws ~320 MiB):
  //  [0,4) flag | [256,10496) bias pool | [10496,14592) ge
  //  [14592,..) wbf 1.75M | [1849600,..) hbf 2M
  //  S = ws+3946752:
  //    heT  = S[0:10M)   [b*5+e][256 d][1024 node] bf16
  //    part = S[12M:32M) [b*5+e][1024][256] fp32 partials
  //    accb = S[32M:34M) bf16
  //    gi = S[0:6M), gh = S[6:12M)   (heT dead by then)
  //    attl = S[0:4M) f32, fetl = S[4:8M) f32  (after loop)
  //  adjb @ ws+40MiB (40 MiB bf16)
  char* ws = (char*)d_ws;
  const size_t MB = (size_t)1 << 20;
  int*            flag = (int*)(ws);
  float*          bp   = (float*)(ws + 256);
  float*          ge   = (float*)(ws + 10496);
  __hip_bfloat16* wbf  = (__hip_bfloat16*)(ws + 14592);
  __hip_bfloat16* hbf  = (__hip_bfloat16*)(ws + 1849600);
  char*           S    = ws + 3946752;
  __hip_bfloat16* heT  = (__hip_bfloat16*)(S);
  float*          part = (float*)(S + 12 * MB);
  __hip_bfloat16* accb = (__hip_bfloat16*)(S + 32 * MB);
  __hip_bfloat16* gi   = (__hip_bfloat16*)(S);
  __hip_bfloat16* gh   = (__hip_bfloat16*)(S + 6 * MB);
  float*          attl = (float*)(S);
  float*          fetl = (float*)(S + 4 * MB);
  __hip_bfloat16* adjb = (__hip_bfloat16*)(ws + 40 * MB);

  const bool has_split = ws_size >= 40 * MB;   // part/accb fit
  const bool has_adjb  = ws_size >= 81 * MB;   // adjb fits

  detect_dtype<<<1, 256, 0, stream>>>((const uint32_t*)adj, flag);
  prep_pool<<<1, 256, 0, stream>>>(fc_b, b_ih, b_hh, c1b, c2b, edge_b, flag, bp, ge);
  wcvt_all<<<3584, 256, 0, stream>>>(fc_w, edge_w, w_ih, w_hh, c1w, c2w, flag, wbf);
  if (has_adjb) adj_cvt<<<10240, 256, 0, stream>>>(adj, flag, adjb);

  // h = X @ fc_w^T + fc_b
  gemm_bt<0, true, true, false><<<dim3(64, 4, 1), 256, 0, stream>>>(
      node_f, wbf + 0, bp + 0, hbf, nullptr, nullptr, nullptr, nullptr, flag,
      256, 1, 256, 256, 256, 0, 1, 1, 0, 1, 1, 0, 1, 0, 0, 0);

  for (int s = 0; s < 5; ++s) {
    // heT[b,e][d][node] = edge_w[e] @ h[b]^T  (row-major coalesced store)
    gemm_bt<0, false, false, false><<<dim3(4, 16, 20), 256, 0, stream>>>(
        wbf + 65536, hbf, nullptr, heT, nullptr, nullptr, nullptr, nullptr, flag,
        256, 1, 256, 256, 1024,
        65536, 1, 5, 262144, 5, 4,
        262144, 1, 0, 0, 0);
    if (has_split) {
      // part[b,e] = adj[b,e] @ he[b,e]  (plain fp32 stores, no atomics)
      if (has_adjb) {
        gemm_bt<1, false, false, false><<<dim3(16, 4, 20), 256, 0, stream>>>(
            adjb, heT, nullptr, part, nullptr, nullptr, nullptr, nullptr, flag,
            1024, 1, 1024, 1024, 256,
            1048576, 1, 20, 262144, 1, 20,
            262144, 1, 0, 0, 0);
      } else {
        gemm_bt<1, false, true, false><<<dim3(16, 4, 20), 256, 0, stream>>>(
            adj, heT, nullptr, part, nullptr, nullptr, nullptr, nullptr, flag,
            1024, 1, 1024, 1024, 256,
            1048576, 1, 20, 262144, 1, 20,
            262144, 1, 0, 0, 0);
      }
      acc_finish<<<4096, 256, 0, stream>>>(part, bp, accb);
    } else {
      // fallback: grouped-K directly into accb
      gemm_bt<0, true, true, false><<<dim3(16, 4, 4), 256, 0, stream>>>(
          adj, heT, bp + 2304, accb, nullptr, nullptr, nullptr, nullptr, flag,
          1024, 5, 1024, 1024, 256,
          (long)5 * 1048576, 1, 4, (long)5 * 262144, 1, 4,
          262144, 1, 1048576, 262144, 0);
    }
    // gi = acc @ w_ih^T + b_ih  AND  gh = h @ w_hh^T + b_hh  (dual dispatch)
    gemm_bt<0, true, false, true><<<dim3(64, 12, 2), 256, 0, stream>>>(
        accb, wbf + 393216, bp + 256, gi,
        hbf,  wbf + 589824, bp + 1024, gh, flag,
        256, 1, 256, 256, 768, 0, 1, 1, 0, 1, 1, 0, 1, 0, 0, 1);
    gru_gate<<<4096, 256, 0, stream>>>(gi, gh, hbf,
                                       (s == 4) ? d_out : nullptr, flag);
  }

  // attn/feat logits in one dual dispatch (fp32 out)
  gemm_bt<1, true, false, true><<<dim3(64, 4, 2), 256, 0, stream>>>(
      hbf, wbf + 786432, bp + 1792, attl,
      hbf, wbf + 851968, bp + 2048, fetl, flag,
      256, 1, 256, 256, 256, 0, 1, 1, 0, 1, 1, 0, 1, 0, 0, 1);

  ge_partial<<<dim3(128, 4), 256, 0, stream>>>(attl, fetl, ge);
  attn_map_k<<<1024, 256, 0, stream>>>(attl, d_out, flag);
  ge_finish<<<4, 256, 0, stream>>>(ge, d_out, flag);
}

// Round 8
// 453.910 us; speedup vs baseline: 2.0405x; 1.0164x over previous
//
#include <hip/hip_runtime.h>
#include <hip/hip_bf16.h>
#include <cstdint>

// GGNN encoder, B=4, N=1024, DIN=D=256, E=5, STEP=5. Inputs fp32 (sniffed).
// Round 8: bf16 partials; acc_finish folded into gi GEMM via 5-slice summing
// A-loader + combined bias (b_ih + sum_edge_b @ w_ih^T); conv/attn/ge epilogue
// fused into one GEMM kernel with LDS+atomic reductions. 26 dispatches.

typedef __attribute__((ext_vector_type(8))) short bf16x8;
typedef __attribute__((ext_vector_type(4))) float f32x4;

__device__ __forceinline__ float bf2f(__hip_bfloat16 x) { return __bfloat162float(x); }
__device__ __forceinline__ __hip_bfloat16 f2bf(float x) { return __float2bfloat16(x); }
__device__ __forceinline__ short f2bs(float x) {
  __hip_bfloat16 h = __float2bfloat16(x);
  return *reinterpret_cast<short*>(&h);
}
__device__ __forceinline__ float s2f(short x) {
  __hip_bfloat16 h = *reinterpret_cast<__hip_bfloat16*>(&x);
  return __bfloat162float(h);
}

__device__ __forceinline__ bf16x8 ld8_ext(const void* base, long off, bool f32) {
  if (f32) {
    const float* p = (const float*)base + off;
    bf16x8 r;
#pragma unroll
    for (int i = 0; i < 8; ++i) r[i] = f2bs(p[i]);
    return r;
  }
  return *(const bf16x8*)((const __hip_bfloat16*)base + off);
}

// sum of 5 bf16 part slices: part[(b*5+e)][1024][256], row = b*1024+node
__device__ __forceinline__ bf16x8 ld8_sum5(const __hip_bfloat16* part, int row, int k) {
  const long base = (long)row * 256 + (long)(row >> 10) * 1048576 + k;
  float s[8] = {0.f, 0.f, 0.f, 0.f, 0.f, 0.f, 0.f, 0.f};
#pragma unroll
  for (int e = 0; e < 5; ++e) {
    bf16x8 v = *(const bf16x8*)(part + base + e * 262144);
#pragma unroll
    for (int j = 0; j < 8; ++j) s[j] += s2f(v[j]);
  }
  bf16x8 r;
#pragma unroll
  for (int j = 0; j < 8; ++j) r[j] = f2bs(s[j]);
  return r;
}

// ---- dtype sniffer: flag = 1 if inputs are fp32, 0 if bf16 ----
__global__ void detect_dtype(const uint32_t* __restrict__ raw, int* __restrict__ flag) {
  __shared__ int cnt;
  if (threadIdx.x == 0) cnt = 0;
  __syncthreads();
  int c = 0;
  for (int i = threadIdx.x; i < 512; i += 256) {
    uint32_t byte = (raw[i] >> 8) & 0xFF;
    if (byte >= 0x28 && byte <= 0x40) ++c;
  }
  atomicAdd(&cnt, c);
  __syncthreads();
  if (threadIdx.x == 0) *flag = (cnt < 300) ? 1 : 0;
}

// fp32 pool: [0:256) fc_b | [256:1024) b_ih | [1024:1792) b_hh | [1792:2048)
// conv1_b | [2048:2304) conv2_b | [2304:2560) sum_e edge_b | [2560:3328) bias_gi
__global__ void prep_pool(const void* fcb, const void* bih, const void* bhh,
                          const void* c1b, const void* c2b, const void* edgeb,
                          const int* __restrict__ flag,
                          float* __restrict__ pool, float* __restrict__ ge,
                          float* __restrict__ am32) {
  const bool f32 = (*flag != 0);
  for (int t = threadIdx.x; t < 2560; t += 256) {
    const void* p; int i;
    if (t < 256)       { p = fcb;  i = t; }
    else if (t < 1024) { p = bih;  i = t - 256; }
    else if (t < 1792) { p = bhh;  i = t - 1024; }
    else if (t < 2048) { p = c1b;  i = t - 1792; }
    else if (t < 2304) { p = c2b;  i = t - 2048; }
    else {
      int k = t - 2304; float s = 0.f;
      for (int e = 0; e < 5; ++e)
        s += f32 ? ((const float*)edgeb)[e * 256 + k]
                 : bf2f(((const __hip_bfloat16*)edgeb)[e * 256 + k]);
      pool[t] = s; continue;
    }
    pool[t] = f32 ? ((const float*)p)[i] : bf2f(((const __hip_bfloat16*)p)[i]);
  }
  for (int t = threadIdx.x; t < 1024; t += 256) ge[t] = 0.f;
  for (int t = threadIdx.x; t < 4096; t += 256) am32[t] = 0.f;
}

// bias_gi[n] = b_ih[n] + sum_k sum_edge_b[k] * w_ih[n][k]   (n < 768)
__global__ void bias_gi_k(const float* __restrict__ pool,
                          const __hip_bfloat16* __restrict__ wih,
                          float* __restrict__ out) {
  const int n = blockIdx.x * 256 + threadIdx.x;
  if (n >= 768) return;
  float s = pool[256 + n];
  for (int k = 0; k < 256; ++k) s += pool[2304 + k] * bf2f(wih[n * 256 + k]);
  out[n] = s;
}

// ingest all 6 weight matrices into one internal bf16 pool
__global__ void wcvt_all(const void* fcw, const void* edw, const void* wih,
                         const void* whh, const void* c1w, const void* c2w,
                         const int* __restrict__ flag, __hip_bfloat16* __restrict__ dst) {
  const bool f32 = (*flag != 0);
  const int i = blockIdx.x * 256 + threadIdx.x;   // 0..917503
  const void* src; int off;
  if      (i < 65536)  { src = fcw; off = i; }
  else if (i < 393216) { src = edw; off = i - 65536; }
  else if (i < 589824) { src = wih; off = i - 393216; }
  else if (i < 786432) { src = whh; off = i - 589824; }
  else if (i < 851968) { src = c1w; off = i - 786432; }
  else                 { src = c2w; off = i - 851968; }
  dst[i] = f32 ? f2bf(((const float*)src)[off])
               : ((const __hip_bfloat16*)src)[off];
}

// one-time adj -> internal bf16 (20,971,520 elems), 8 elems/thread
__global__ void adj_cvt(const void* __restrict__ src, const int* __restrict__ flag,
                        __hip_bfloat16* __restrict__ dst) {
  const bool f32 = (*flag != 0);
  const long i = ((long)blockIdx.x * 256 + threadIdx.x) * 8;
  bf16x8 r;
  if (f32) {
    const float* p = (const float*)src + i;
#pragma unroll
    for (int j = 0; j < 8; ++j) r[j] = f2bs(p[j]);
  } else {
    r = *(const bf16x8*)((const __hip_bfloat16*)src + i);
  }
  *(bf16x8*)(dst + i) = r;
}

// OUT_MODE: 0=bf16 C; 1=fp32 C.  A_MODE: 0=internal bf16, 1=external (flag
// dtype), 2=sum-of-5-bf16-slices (gi).  DUAL: z>=zSplit switches to 2nd set
// (2nd set A is always internal bf16).
template<int OUT_MODE, bool HAS_BIAS, int A_MODE, bool DUAL>
__global__ __launch_bounds__(256)
void gemm_bt(const void* __restrict__ A, const __hip_bfloat16* __restrict__ Bt,
             const float* __restrict__ bias, void* __restrict__ Cp,
             const void* __restrict__ A2, const __hip_bfloat16* __restrict__ Bt2,
             const float* __restrict__ bias2, void* __restrict__ Cp2,
             const int* __restrict__ flag,
             int Kg, int ngrp, int lda, int ldb, int ldc,
             long aBatch, int zdivA, int zmodA,
             long bBatch, int zdivB, int zmodB,
             long cBatch, int zdivC, long aGrp, long bGrp, int zSplit)
{
  __shared__ __align__(16) __hip_bfloat16 sA[64 * 64];
  __shared__ __align__(16) __hip_bfloat16 sB[64 * 64];
  const bool af32 = (A_MODE == 1) ? (*flag != 0) : false;
  const int t = threadIdx.x;
  const int w = t >> 6;
  const int l = t & 63;
  const int m0 = blockIdx.x * 64;
  const int n0 = blockIdx.y * 64;
  int z = blockIdx.z;

  const void* Au = A; const __hip_bfloat16* Btu = Bt;
  const float* biasu = bias; void* Cpu = Cp;
  bool second = false;
  if (DUAL && z >= zSplit) {
    Au = A2; Btu = Bt2; biasu = bias2; Cpu = Cp2; z -= zSplit; second = true;
  }

  const long aOff = (long)((z / zdivA) % zmodA) * aBatch;
  const __hip_bfloat16* Bb = Btu + (long)((z / zdivB) % zmodB) * bBatch;

  // staging: 16B chunk p -> LDS(row=p>>3, slot=p&7); slot s of row r holds
  // data chunk s ^ (r&7) (XOR swizzle; SQ_LDS_BANK_CONFLICT measured 0)
  const int p0 = t, p1 = t + 256;
  const int sr0 = p0 >> 3, sc0 = (p0 & 7) ^ (sr0 & 7);
  const int sr1 = p1 >> 3, sc1 = (p1 & 7) ^ (sr1 & 7);

  f32x4 acc[4];
#pragma unroll
  for (int i = 0; i < 4; ++i) acc[i] = (f32x4){0.f, 0.f, 0.f, 0.f};

  const int mrow = w * 16 + (l & 15);
  const int quad = l >> 4;

  for (int g = 0; g < ngrp; ++g) {
    const long aG = aOff + (long)g * aGrp;
    const __hip_bfloat16* Bg = Bb + (long)g * bGrp;
    for (int k0 = 0; k0 < Kg; k0 += 64) {
      bf16x8 a0, a1;
      if (A_MODE == 2 && !second) {
        a0 = ld8_sum5((const __hip_bfloat16*)Au, m0 + sr0, k0 + sc0 * 8);
        a1 = ld8_sum5((const __hip_bfloat16*)Au, m0 + sr1, k0 + sc1 * 8);
      } else if (A_MODE == 1) {
        a0 = ld8_ext(Au, aG + (long)(m0 + sr0) * lda + (k0 + sc0 * 8), af32);
        a1 = ld8_ext(Au, aG + (long)(m0 + sr1) * lda + (k0 + sc1 * 8), af32);
      } else {
        const __hip_bfloat16* Ab = (const __hip_bfloat16*)Au;
        a0 = *(const bf16x8*)(Ab + aG + (long)(m0 + sr0) * lda + (k0 + sc0 * 8));
        a1 = *(const bf16x8*)(Ab + aG + (long)(m0 + sr1) * lda + (k0 + sc1 * 8));
      }
      bf16x8 b0 = *(const bf16x8*)(Bg + (long)(n0 + sr0) * ldb + (k0 + sc0 * 8));
      bf16x8 b1 = *(const bf16x8*)(Bg + (long)(n0 + sr1) * ldb + (k0 + sc1 * 8));
      __syncthreads();
      *(bf16x8*)(sA + p0 * 8) = a0;
      *(bf16x8*)(sA + p1 * 8) = a1;
      *(bf16x8*)(sB + p0 * 8) = b0;
      *(bf16x8*)(sB + p1 * 8) = b1;
      __syncthreads();
#pragma unroll
      for (int ks = 0; ks < 2; ++ks) {
        const int cg = ks * 4 + quad;
        bf16x8 af = *(const bf16x8*)(sA + mrow * 64 + ((cg ^ (mrow & 7)) * 8));
#pragma unroll
        for (int t4 = 0; t4 < 4; ++t4) {
          const int nrow = t4 * 16 + (l & 15);
          bf16x8 bfr = *(const bf16x8*)(sB + nrow * 64 + ((cg ^ (nrow & 7)) * 8));
          acc[t4] = __builtin_amdgcn_mfma_f32_16x16x32_bf16(af, bfr, acc[t4], 0, 0, 0);
        }
      }
    }
  }

  // C/D layout: col = lane&15, row = (lane>>4)*4 + reg
  const long cOff = (long)(z / zdivC) * cBatch;
#pragma unroll
  for (int t4 = 0; t4 < 4; ++t4) {
    const int n = n0 + t4 * 16 + (l & 15);
    float bv = 0.f;
    if (HAS_BIAS) bv = biasu[n];
#pragma unroll
    for (int r = 0; r < 4; ++r) {
      const int m = m0 + w * 16 + quad * 4 + r;
      const float v = acc[t4][r] + bv;
      if (OUT_MODE == 0)
        ((__hip_bfloat16*)Cpu)[cOff + (long)m * ldc + n] = f2bf(v);
      else
        ((float*)Cpu)[cOff + (long)m * ldc + n] = v;
    }
  }
}

// torch GRUCell gates [r,z,n]; final step also writes node_states to d_out
__global__ void gru_gate(const __hip_bfloat16* __restrict__ gi,
                         const __hip_bfloat16* __restrict__ gh,
                         __hip_bfloat16* __restrict__ hbf,
                         void* __restrict__ ns_out, const int* __restrict__ flag)
{
  const int m = blockIdx.x;
  const int k = threadIdx.x;
  const long gb = (long)m * 768;
  const float ir = bf2f(gi[gb + k]);
  const float iz = bf2f(gi[gb + 256 + k]);
  const float inn = bf2f(gi[gb + 512 + k]);
  const float hr = bf2f(gh[gb + k]);
  const float hz = bf2f(gh[gb + 256 + k]);
  const float hn = bf2f(gh[gb + 512 + k]);
  const long hidx = (long)m * 256 + k;
  const float h = bf2f(hbf[hidx]);
  const float r = 1.f / (1.f + __expf(-(ir + hr)));
  const float zz = 1.f / (1.f + __expf(-(iz + hz)));
  const float nn = tanhf(inn + r * hn);
  const float hnew = (1.f - zz) * nn + zz * h;
  const __hip_bfloat16 hb = f2bf(hnew);
  hbf[hidx] = hb;
  if (ns_out) {
    if (*flag) ((float*)ns_out)[1024 + hidx] = hnew;
    else       ((__hip_bfloat16*)ns_out)[1024 + hidx] = hb;
  }
}

// fused output epilogue: per 64x64 tile compute attl & fetl via MFMA, apply
// sigmoid/tanh, reduce ge (sum over nodes) and attn row-sums via LDS+atomics.
__global__ __launch_bounds__(256)
void conv_fused(const __hip_bfloat16* __restrict__ hbf,
                const __hip_bfloat16* __restrict__ c1w,
                const __hip_bfloat16* __restrict__ c2w,
                const float* __restrict__ pool,
                float* __restrict__ geg, float* __restrict__ am32)
{
  __shared__ __align__(16) __hip_bfloat16 sA[64 * 64];
  __shared__ __align__(16) __hip_bfloat16 sB1[64 * 64];
  __shared__ __align__(16) __hip_bfloat16 sB2[64 * 64];
  __shared__ float sge[64];
  __shared__ float sam[64];
  const int t = threadIdx.x, w = t >> 6, l = t & 63;
  const int m0 = blockIdx.x * 64, n0 = blockIdx.y * 64;
  if (t < 64) { sge[t] = 0.f; sam[t] = 0.f; }
  const int p0 = t, p1 = t + 256;
  const int sr0 = p0 >> 3, sc0 = (p0 & 7) ^ (sr0 & 7);
  const int sr1 = p1 >> 3, sc1 = (p1 & 7) ^ (sr1 & 7);
  f32x4 a1[4], a2[4];
#pragma unroll
  for (int i = 0; i < 4; ++i) { a1[i] = (f32x4){0,0,0,0}; a2[i] = (f32x4){0,0,0,0}; }
  const int mrow = w * 16 + (l & 15);
  const int quad = l >> 4;
  for (int k0 = 0; k0 < 256; k0 += 64) {
    bf16x8 va0 = *(const bf16x8*)(hbf + (long)(m0 + sr0) * 256 + (k0 + sc0 * 8));
    bf16x8 va1 = *(const bf16x8*)(hbf + (long)(m0 + sr1) * 256 + (k0 + sc1 * 8));
    bf16x8 vb0 = *(const bf16x8*)(c1w + (long)(n0 + sr0) * 256 + (k0 + sc0 * 8));
    bf16x8 vb1 = *(const bf16x8*)(c1w + (long)(n0 + sr1) * 256 + (k0 + sc1 * 8));
    bf16x8 vc0 = *(const bf16x8*)(c2w + (long)(n0 + sr0) * 256 + (k0 + sc0 * 8));
    bf16x8 vc1 = *(const bf16x8*)(c2w + (long)(n0 + sr1) * 256 + (k0 + sc1 * 8));
    __syncthreads();
    *(bf16x8*)(sA + p0 * 8) = va0;  *(bf16x8*)(sA + p1 * 8) = va1;
    *(bf16x8*)(sB1 + p0 * 8) = vb0; *(bf16x8*)(sB1 + p1 * 8) = vb1;
    *(bf16x8*)(sB2 + p0 * 8) = vc0; *(bf16x8*)(sB2 + p1 * 8) = vc1;
    __syncthreads();
#pragma unroll
    for (int ks = 0; ks < 2; ++ks) {
      const int cg = ks * 4 + quad;
      bf16x8 af = *(const bf16x8*)(sA + mrow * 64 + ((cg ^ (mrow & 7)) * 8));
#pragma unroll
      for (int t4 = 0; t4 < 4; ++t4) {
        const int nrow = t4 * 16 + (l & 15);
        bf16x8 b1f = *(const bf16x8*)(sB1 + nrow * 64 + ((cg ^ (nrow & 7)) * 8));
        bf16x8 b2f = *(const bf16x8*)(sB2 + nrow * 64 + ((cg ^ (nrow & 7)) * 8));
        a1[t4] = __builtin_amdgcn_mfma_f32_16x16x32_bf16(af, b1f, a1[t4], 0, 0, 0);
        a2[t4] = __builtin_amdgcn_mfma_f32_16x16x32_bf16(af, b2f, a2[t4], 0, 0, 0);
      }
    }
  }
  float asum[4] = {0.f, 0.f, 0.f, 0.f};
#pragma unroll
  for (int t4 = 0; t4 < 4; ++t4) {
    const int n = n0 + t4 * 16 + (l & 15);
    const float bb1 = pool[1792 + n], bb2 = pool[2048 + n];
    float g = 0.f;
#pragma unroll
    for (int r = 0; r < 4; ++r) {
      const float av = 1.f / (1.f + __expf(-(a1[t4][r] + bb1)));
      const float fv = tanhf(a2[t4][r] + bb2);
      g += av * fv;
      asum[r] += av;
    }
    atomicAdd(&sge[t4 * 16 + (l & 15)], g);
  }
#pragma unroll
  for (int r = 0; r < 4; ++r) atomicAdd(&sam[w * 16 + quad * 4 + r], asum[r]);
  __syncthreads();
  if (t < 64) atomicAdd(&geg[(m0 >> 10) * 256 + n0 + t], sge[t]);
  else if (t < 128) atomicAdd(&am32[m0 + (t - 64)], sam[t - 64]);
}

__global__ void finish_out(const float* __restrict__ ge, const float* __restrict__ am32,
                           void* __restrict__ dout, const int* __restrict__ flag)
{
  const int t = blockIdx.x * 256 + threadIdx.x;   // 0..5119
  const bool f32 = (*flag != 0);
  if (t < 1024) {
    if (f32) ((float*)dout)[t] = ge[t];
    else     ((__hip_bfloat16*)dout)[t] = f2bf(ge[t]);
  } else {
    const float v = am32[t - 1024] * (1.f / 256.f);
    if (f32) ((float*)dout)[1049600 + t - 1024] = v;
    else     ((__hip_bfloat16*)dout)[1049600 + t - 1024] = f2bf(v);
  }
}

extern "C" void kernel_launch(void* const* d_in, const int* in_sizes, int n_in,
                              void* d_out, int out_size, void* d_ws, size_t ws_size,
                              hipStream_t stream) {
  (void)in_sizes; (void)n_in; (void)out_size;
  const void* node_f = d_in[0];
  const void* adj    = d_in[1];
  const void* fc_w   = d_in[2];
  const void* fc_b   = d_in[3];
  const void* edge_w = d_in[4];
  const void* edge_b = d_in[5];
  const void* w_ih   = d_in[6];
  const void* w_hh   = d_in[7];
  const void* b_ih   = d_in[8];
  const void* b_hh   = d_in[9];
  const void* c1w    = d_in[10];
  const void* c1b    = d_in[11];
  const void* c2w    = d_in[12];
  const void* c2b    = d_in[13];

  // ws layout:
  //  [0,4) flag | [256, 13568) pool (3328 f) | [14336, 18432) ge (1024 f)
  //  [18432, 34816) am32 (4096 f) | [34816, ..) wbf 1.75M | [1869824, ..) hbf 2M
  //  S = ws+3966976: heT [0,10M) | part bf16 [10M,20M) | gi [20M,26M) | gh [26M,32M)
  //  adjb @ ws+40MiB (40 MiB)
  char* ws = (char*)d_ws;
  const size_t MB = (size_t)1 << 20;
  int*            flag = (int*)(ws);
  float*          bp   = (float*)(ws + 256);
  float*          ge   = (float*)(ws + 14336);
  float*          am32 = (float*)(ws + 18432);
  __hip_bfloat16* wbf  = (__hip_bfloat16*)(ws + 34816);
  __hip_bfloat16* hbf  = (__hip_bfloat16*)(ws + 1869824);
  char*           S    = ws + 3966976;
  __hip_bfloat16* heT  = (__hip_bfloat16*)(S);
  __hip_bfloat16* part = (__hip_bfloat16*)(S + 10 * MB);
  __hip_bfloat16* gi   = (__hip_bfloat16*)(S + 20 * MB);
  __hip_bfloat16* gh   = (__hip_bfloat16*)(S + 26 * MB);
  __hip_bfloat16* adjb = (__hip_bfloat16*)(ws + 40 * MB);

  const bool has_split = ws_size >= 38 * MB;   // part/gi/gh fit
  const bool has_adjb  = ws_size >= 81 * MB;   // adjb fits

  detect_dtype<<<1, 256, 0, stream>>>((const uint32_t*)adj, flag);
  prep_pool<<<1, 256, 0, stream>>>(fc_b, b_ih, b_hh, c1b, c2b, edge_b, flag, bp, ge, am32);
  wcvt_all<<<3584, 256, 0, stream>>>(fc_w, edge_w, w_ih, w_hh, c1w, c2w, flag, wbf);
  bias_gi_k<<<3, 256, 0, stream>>>(bp, wbf + 393216, bp + 2560);
  if (has_adjb) adj_cvt<<<10240, 256, 0, stream>>>(adj, flag, adjb);

  // h = X @ fc_w^T + fc_b
  gemm_bt<0, true, 1, false><<<dim3(64, 4, 1), 256, 0, stream>>>(
      node_f, wbf + 0, bp + 0, hbf, nullptr, nullptr, nullptr, nullptr, flag,
      256, 1, 256, 256, 256, 0, 1, 1, 0, 1, 1, 0, 1, 0, 0, 0);

  for (int s = 0; s < 5; ++s) {
    // heT[b,e][d][node] = edge_w[e] @ h[b]^T
    gemm_bt<0, false, 0, false><<<dim3(4, 16, 20), 256, 0, stream>>>(
        wbf + 65536, hbf, nullptr, heT, nullptr, nullptr, nullptr, nullptr, flag,
        256, 1, 256, 256, 1024,
        65536, 1, 5, 262144, 5, 4,
        262144, 1, 0, 0, 0);
    if (has_split) {
      // part[b,e] = adj[b,e] @ he[b,e]  (bf16, no atomics)
      if (has_adjb) {
        gemm_bt<0, false, 0, false><<<dim3(16, 4, 20), 256, 0, stream>>>(
            adjb, heT, nullptr, part, nullptr, nullptr, nullptr, nullptr, flag,
            1024, 1, 1024, 1024, 256,
            1048576, 1, 20, 262144, 1, 20,
            262144, 1, 0, 0, 0);
      } else {
        gemm_bt<0, false, 1, false><<<dim3(16, 4, 20), 256, 0, stream>>>(
            adj, heT, nullptr, part, nullptr, nullptr, nullptr, nullptr, flag,
            1024, 1, 1024, 1024, 256,
            1048576, 1, 20, 262144, 1, 20,
            262144, 1, 0, 0, 0);
      }
      // gi = (sum_e part) @ w_ih^T + bias_gi  AND  gh = h @ w_hh^T + b_hh
      gemm_bt<0, true, 2, true><<<dim3(64, 12, 2), 256, 0, stream>>>(
          part, wbf + 393216, bp + 2560, gi,
          hbf,  wbf + 589824, bp + 1024, gh, flag,
          256, 1, 256, 256, 768, 0, 1, 1, 0, 1, 1, 0, 1, 0, 0, 1);
    } else {
      // fallback: grouped-K acc (incl. sum_edge_b) into part region
      gemm_bt<0, true, 1, false><<<dim3(16, 4, 4), 256, 0, stream>>>(
          adj, heT, bp + 2304, part, nullptr, nullptr, nullptr, nullptr, flag,
          1024, 5, 1024, 1024, 256,
          (long)5 * 1048576, 1, 4, (long)5 * 262144, 1, 4,
          262144, 1, 1048576, 262144, 0);
      gemm_bt<0, true, 0, true><<<dim3(64, 12, 2), 256, 0, stream>>>(
          part, wbf + 393216, bp + 256, gi,
          hbf,  wbf + 589824, bp + 1024, gh, flag,
          256, 1, 256, 256, 768, 0, 1, 1, 0, 1, 1, 0, 1, 0, 0, 1);
    }
    gru_gate<<<4096, 256, 0, stream>>>(gi, gh, hbf,
                                       (s == 4) ? d_out : nullptr, flag);
  }

  conv_fused<<<dim3(64, 4), 256, 0, stream>>>(hbf, wbf + 786432, wbf + 851968,
                                              bp, ge, am32);
  finish_out<<<20, 256, 0, stream>>>(ge, am32, d_out, flag);
}